// Round 2
// baseline (1488.950 us; speedup 1.0000x reference)
//
#include <hip/hip_runtime.h>
#include <cstdint>
#include <cstddef>

#define NN_TOK 16384
#define ROWS   65536      // B*N
#define CDIM   192
#define HID    384
#define NHEAD  8
#define HD     48
#define QKVO   1152

// ---------------- K0: combine the two input projections ----------------
// Wc[o,c] = sum_m qkv_w[o,m]*in_w[m,c] ; bc[o] = qkv_b[o] + sum_m qkv_w[o,m]*in_b[m]
__global__ void combine_w(const float* __restrict__ in_w, const float* __restrict__ in_b,
                          const float* __restrict__ qkv_w, const float* __restrict__ qkv_b,
                          float* __restrict__ Wc, float* __restrict__ bc) {
  int o = blockIdx.x;        // 0..1151
  int c = threadIdx.x;       // 0..191
  const float* qw = qkv_w + o * HID;
  float s = 0.f;
  for (int m = 0; m < HID; ++m) s += qw[m] * in_w[m * CDIM + c];
  Wc[o * CDIM + c] = s;
  if (c == 0) {
    float sb = qkv_b[o];
    for (int m = 0; m < HID; ++m) sb += qw[m] * in_b[m];
    bc[o] = sb;
  }
}

// zero a float region (avoid hipMemsetAsync inside graph capture)
__global__ void zero_k(float* __restrict__ p, int n) {
  int i = blockIdx.x * blockDim.x + threadIdx.x;
  if (i < n) p[i] = 0.f;
}

// ---------------- tiled fp32 GEMM: C[n,o] = sum_k A[n,k]*W[o,k] + bias[o] ----------------
// A (NN,K) row-major, W (O,K) row-major. 64x64 tile, 256 threads, 4x4 micro-tile, BK=16.
__global__ __launch_bounds__(256) void gemm_bias(const float* __restrict__ A, const float* __restrict__ W,
                                                 const float* __restrict__ bias, float* __restrict__ C,
                                                 int K, int O) {
  __shared__ float As[16][64];
  __shared__ float Ws[16][64];
  const int t  = threadIdx.x;
  const int tx = t & 15, ty = t >> 4;
  const int n0 = blockIdx.y * 64;
  const int o0 = blockIdx.x * 64;
  const int r  = t >> 2;            // 0..63
  const int kq = (t & 3) * 4;       // 0,4,8,12
  float acc[4][4] = {};
  const float* Arow = A + (size_t)(n0 + r) * K + kq;
  const float* Wrow = W + (size_t)(o0 + r) * K + kq;
  for (int kt = 0; kt < K; kt += 16) {
    float4 a4 = *(const float4*)(Arow + kt);
    float4 w4 = *(const float4*)(Wrow + kt);
    As[kq + 0][r] = a4.x; As[kq + 1][r] = a4.y; As[kq + 2][r] = a4.z; As[kq + 3][r] = a4.w;
    Ws[kq + 0][r] = w4.x; Ws[kq + 1][r] = w4.y; Ws[kq + 2][r] = w4.z; Ws[kq + 3][r] = w4.w;
    __syncthreads();
#pragma unroll
    for (int kk = 0; kk < 16; ++kk) {
      float4 av = *(const float4*)(&As[kk][ty * 4]);
      float4 wv = *(const float4*)(&Ws[kk][tx * 4]);
      float aa[4] = {av.x, av.y, av.z, av.w};
      float ww[4] = {wv.x, wv.y, wv.z, wv.w};
#pragma unroll
      for (int i = 0; i < 4; ++i)
#pragma unroll
        for (int j = 0; j < 4; ++j) acc[i][j] += aa[i] * ww[j];
    }
    __syncthreads();
  }
  float4 bv = *(const float4*)(bias + o0 + tx * 4);
  float bb[4] = {bv.x, bv.y, bv.z, bv.w};
#pragma unroll
  for (int i = 0; i < 4; ++i) {
    float4 outv;
    outv.x = acc[i][0] + bb[0];
    outv.y = acc[i][1] + bb[1];
    outv.z = acc[i][2] + bb[2];
    outv.w = acc[i][3] + bb[3];
    *(float4*)(C + (size_t)(n0 + ty * 4 + i) * O + o0 + tx * 4) = outv;
  }
}

// ---------------- RoPE + elu+1 in place on a (ROWS,384) buffer ----------------
// one thread per rotation pair (d, d+24) per head per row: 192 pairs/row
__global__ void rope_elu_k(float* __restrict__ buf, int total) {
  int idx = blockIdx.x * blockDim.x + threadIdx.x;
  if (idx >= total) return;
  int row = idx / 192;
  int p   = idx - row * 192;
  int h   = p / 24;
  int dp  = p - h * 24;              // 0..23
  int j   = dp % 12;
  int n   = row & (NN_TOK - 1);
  float fy = (float)(n >> 7);
  float fx = (float)(n & 127);
  const float c0 = 1.1073093649624542f;   // log2(10000)/12
  float freq = exp2f(-(float)j * c0);
  float f1 = fy * freq;                    // th (first 24 dims)
  float f2 = fx * freq;                    // tw (last 24 dims)
  float s1, c1, s2, c2;
  sincosf(f1, &s1, &c1);
  sincosf(f2, &s2, &c2);
  float* base = buf + (size_t)row * HID + h * HD + dp;
  float in1 = base[0];
  float in2 = base[24];
  float o1 = in1 * c1 - in2 * s1;          // d < 24
  float o2 = in2 * c2 + in1 * s2;          // d >= 24
  o1 = (o1 > 0.f) ? o1 + 1.f : expf(o1);   // elu + 1
  o2 = (o2 > 0.f) ? o2 + 1.f : expf(o2);
  base[0]  = o1;
  base[24] = o2;
}

// ---------------- depthwise 3x3 lepe conv: vnew = v + conv(v) + lepe_b ----------------
// v, vnew are (ROWS, 384) row-major
__global__ void lepe_k(const float* __restrict__ v, const float* __restrict__ lw,
                       const float* __restrict__ lb, float* __restrict__ vnew, int total) {
  int idx = blockIdx.x * blockDim.x + threadIdx.x;
  if (idx >= total) return;
  int pix = idx / HID;
  int ch  = idx - pix * HID;
  int n   = pix & (NN_TOK - 1);
  int boff = pix - n;               // b*16384
  int y = n >> 7, x = n & 127;
  float wr[9];
#pragma unroll
  for (int i = 0; i < 9; ++i) wr[i] = lw[ch * 9 + i];
  float acc = lb[ch];
#pragma unroll
  for (int dy = -1; dy <= 1; ++dy) {
    int yy = y + dy;
    if ((unsigned)yy >= 128u) continue;
#pragma unroll
    for (int dx = -1; dx <= 1; ++dx) {
      int xx = x + dx;
      if ((unsigned)xx >= 128u) continue;
      acc += v[(size_t)(boff + (yy << 7) + xx) * HID + ch] * wr[(dy + 1) * 3 + (dx + 1)];
    }
  }
  vnew[(size_t)pix * HID + ch] = v[(size_t)pix * HID + ch] + acc;
}

// ---------------- kv[bh,d,e] = sum_n k[n,d]*v[n,e]; ksum[bh,d] = sum_n k[n,d] ----------------
// k, vnew are (ROWS,384); grid 256 = (b,h) x 8 chunks of 2048 rows; partials then atomicAdd
__global__ __launch_bounds__(256) void kv_reduce_k(const float* __restrict__ k, const float* __restrict__ vnew,
                                                   float* __restrict__ kv, float* __restrict__ ksum) {
  const int bid   = blockIdx.x;
  const int chunk = bid & 7;
  const int bh    = bid >> 3;         // 0..31
  const int b     = bh >> 3;
  const int h     = bh & 7;
  const int t     = threadIdx.x;
  __shared__ float ks[16][48];
  __shared__ float vs[16][48];
  float acc[9] = {};
  int dd[9], ee[9];
#pragma unroll
  for (int i = 0; i < 9; ++i) {
    int cell = t + i * 256;           // 2304 cells = 48x48
    dd[i] = cell / 48;
    ee[i] = cell - dd[i] * 48;
  }
  float ksacc = 0.f;
  const int n0 = b * NN_TOK + chunk * 2048;
  for (int nb = 0; nb < 2048; nb += 16) {
    for (int l = t; l < 768; l += 256) {
      int rr = l / 48, d = l - rr * 48;
      int n = n0 + nb + rr;
      ks[rr][d] = k[(size_t)n * HID + h * HD + d];
      vs[rr][d] = vnew[(size_t)n * HID + h * HD + d];
    }
    __syncthreads();
#pragma unroll 4
    for (int rr = 0; rr < 16; ++rr) {
#pragma unroll
      for (int i = 0; i < 9; ++i) acc[i] += ks[rr][dd[i]] * vs[rr][ee[i]];
      if (t < 48) ksacc += ks[rr][t];
    }
    __syncthreads();
  }
  float* kvb = kv + (size_t)bh * HD * HD;
#pragma unroll
  for (int i = 0; i < 9; ++i) atomicAdd(&kvb[dd[i] * 48 + ee[i]], acc[i]);
  if (t < 48) atomicAdd(&ksum[bh * 48 + t], ksacc);
}

// ---------------- out = (q@kv)/max(q.ksum,1e-6), LayerNorm -> oln ----------------
// q is (ROWS,384)
__global__ __launch_bounds__(192) void attn_ln_k(const float* __restrict__ q, const float* __restrict__ kv,
                                                 const float* __restrict__ ksum, const float* __restrict__ ln_g,
                                                 const float* __restrict__ ln_b, float* __restrict__ oln) {
  const int row = blockIdx.x;         // 0..65535
  const int b   = row >> 14;
  const int t   = threadIdx.x;        // 0..191
  __shared__ float qrow[384];
  __shared__ float denom[8];
  __shared__ float rs[192], rq[192];
  for (int u = t; u < 384; u += 192) qrow[u] = q[(size_t)row * HID + u];
  __syncthreads();
  if (t < 8) {
    const float* kss = ksum + (b * 8 + t) * 48;
    const float* qh  = qrow + t * 48;
    float s = 0.f;
#pragma unroll
    for (int d = 0; d < 48; ++d) s += qh[d] * kss[d];
    denom[t] = fmaxf(s, 1e-6f);
  }
  __syncthreads();
  float myo[2];
  float ssum = 0.f, ssq = 0.f;
#pragma unroll
  for (int i = 0; i < 2; ++i) {
    int u = t + i * 192;
    int h = u / 48, e = u - h * 48;
    const float* kvb = kv + (size_t)(b * 8 + h) * 48 * 48 + e;
    const float* qh  = qrow + h * 48;
    float s = 0.f;
#pragma unroll
    for (int d = 0; d < 48; ++d) s += qh[d] * kvb[d * 48];
    s /= denom[h];
    myo[i] = s;
    ssum += s;
    ssq  += s * s;
  }
  rs[t] = ssum; rq[t] = ssq;
  __syncthreads();
  for (int off = 96; off >= 3; off >>= 1) {
    if (t < off) { rs[t] += rs[t + off]; rq[t] += rq[t + off]; }
    __syncthreads();
  }
  float tot  = rs[0] + rs[1] + rs[2];
  float totq = rq[0] + rq[1] + rq[2];
  float mu   = tot * (1.f / 384.f);
  float var  = totq * (1.f / 384.f) - mu * mu;
  float rstd = rsqrtf(var + 1e-5f);
#pragma unroll
  for (int i = 0; i < 2; ++i) {
    int u = t + i * 192;
    oln[(size_t)row * HID + u] = (myo[i] - mu) * rstd * ln_g[u] + ln_b[u];
  }
}

extern "C" void kernel_launch(void* const* d_in, const int* in_sizes, int n_in,
                              void* d_out, int out_size, void* d_ws, size_t ws_size,
                              hipStream_t stream) {
  const float* x      = (const float*)d_in[0];
  const float* in_w   = (const float*)d_in[1];
  const float* in_b   = (const float*)d_in[2];
  const float* qkv_w  = (const float*)d_in[3];
  const float* qkv_b  = (const float*)d_in[4];
  const float* lepe_w = (const float*)d_in[5];
  const float* lepe_b = (const float*)d_in[6];
  const float* ln_g   = (const float*)d_in[7];
  const float* ln_b   = (const float*)d_in[8];
  const float* out_w  = (const float*)d_in[9];
  const float* out_b  = (const float*)d_in[10];
  float* out = (float*)d_out;

  // workspace layout (floats): bufA 25165824 | bufB 25165824 | Wc 221184 | bc 1152 | kv 73728 | ksum 1536
  // total = 50,629,248 floats = 202.5 MB
  float* ws   = (float*)d_ws;
  float* bufA = ws;
  float* bufB = bufA + (size_t)ROWS * HID;
  float* Wc   = bufB + (size_t)ROWS * HID;
  float* bc   = Wc + (size_t)QKVO * CDIM;
  float* kvb  = bc + QKVO;
  float* ksum = kvb + 32 * HD * HD;       // contiguous after kvb

  const float* Wq = Wc;                    // rows 0..383
  const float* Wk = Wc + (size_t)384 * CDIM;
  const float* Wv = Wc + (size_t)768 * CDIM;

  // K0: fold in_w/in_b into qkv_w/qkv_b
  combine_w<<<QKVO, CDIM, 0, stream>>>(in_w, in_b, qkv_w, qkv_b, Wc, bc);

  dim3 gp(HID / 64, ROWS / 64);   // (6, 1024) for the three projection GEMMs
  int total_v     = ROWS * HID;
  int total_pairs = ROWS * 192;

  // ---- v path: GEMM v -> bufA, lepe -> bufB (then bufA dead) ----
  gemm_bias<<<gp, 256, 0, stream>>>(x, Wv, bc + 768, bufA, CDIM, HID);
  lepe_k<<<(total_v + 255) / 256, 256, 0, stream>>>(bufA, lepe_w, lepe_b, bufB, total_v);

  // ---- k path: GEMM k -> bufA, rope+elu, kv/ksum reduce ----
  gemm_bias<<<gp, 256, 0, stream>>>(x, Wk, bc + 384, bufA, CDIM, HID);
  rope_elu_k<<<(total_pairs + 255) / 256, 256, 0, stream>>>(bufA, total_pairs);
  zero_k<<<(32 * HD * HD + 32 * HD + 255) / 256, 256, 0, stream>>>(kvb, 32 * HD * HD + 32 * HD);
  kv_reduce_k<<<256, 256, 0, stream>>>(bufA, bufB, kvb, ksum);

  // ---- q path: GEMM q -> bufA, rope+elu, attention + LN -> bufB ----
  gemm_bias<<<gp, 256, 0, stream>>>(x, Wq, bc, bufA, CDIM, HID);
  rope_elu_k<<<(total_pairs + 255) / 256, 256, 0, stream>>>(bufA, total_pairs);
  attn_ln_k<<<ROWS, 192, 0, stream>>>(bufA, kvb, ksum, ln_g, ln_b, bufB);

  // ---- final projection: (65536 x 384) @ out_w^T -> out ----
  dim3 g6(CDIM / 64, ROWS / 64);
  gemm_bias<<<g6, 256, 0, stream>>>(bufB, out_w, out_b, out, HID, CDIM);
}

// Round 3
// 805.555 us; speedup vs baseline: 1.8484x; 1.8484x over previous
//
#include <hip/hip_runtime.h>
#include <cstdint>
#include <cstddef>

#define NN_TOK 16384
#define ROWS   65536      // B*N
#define CDIM   192
#define HID    384
#define NHEAD  8
#define HD     48
#define QKVO   1152

typedef unsigned short ushort_t;
typedef __bf16 bf16x8 __attribute__((ext_vector_type(8)));
typedef float  f32x4  __attribute__((ext_vector_type(4)));

__device__ __forceinline__ ushort_t f2bf(float f) {
  unsigned int u = __float_as_uint(f);
  u += 0x7fffu + ((u >> 16) & 1u);          // round-to-nearest-even
  return (ushort_t)(u >> 16);
}
__device__ __forceinline__ float bf2f(ushort_t u) {
  return __uint_as_float(((unsigned int)u) << 16);
}

// ---------------- K0: combine input projections; Wc in bf16, bc fp32 ----------------
__global__ void combine_w(const float* __restrict__ in_w, const float* __restrict__ in_b,
                          const float* __restrict__ qkv_w, const float* __restrict__ qkv_b,
                          ushort_t* __restrict__ Wcb, float* __restrict__ bc) {
  int o = blockIdx.x;        // 0..1151
  int c = threadIdx.x;       // 0..191
  const float* qw = qkv_w + o * HID;
  float s = 0.f;
  for (int m = 0; m < HID; ++m) s += qw[m] * in_w[m * CDIM + c];
  Wcb[o * CDIM + c] = f2bf(s);
  if (c == 0) {
    float sb = qkv_b[o];
    for (int m = 0; m < HID; ++m) sb += qw[m] * in_b[m];
    bc[o] = sb;
  }
}

// cast out_w (192x384 fp32) -> bf16
__global__ void cast_ow(const float* __restrict__ w, ushort_t* __restrict__ wb, int n) {
  int i = blockIdx.x * blockDim.x + threadIdx.x;
  if (i < n) wb[i] = f2bf(w[i]);
}

// ---------------- MFMA bf16 GEMM: C[n,o] = sum_k A[n,k]*W[o,k] + bias[o] ----------------
// BMxBN block tile, 4 waves in WMxWN grid, BK=32, mfma_f32_16x16x32_bf16.
// A fp32 (converted during staging) or bf16; C fp32 or bf16.
template<int BM, int BN, int WM, int WN, bool AF32, bool OUTBF16>
__global__ __launch_bounds__(256) void gemm_mfma(const void* __restrict__ Aptr,
                                                 const ushort_t* __restrict__ Wb,
                                                 const float* __restrict__ bias,
                                                 void* __restrict__ Cptr,
                                                 int K, int O) {
  constexpr int TM = BM / WM / 16;    // m-tiles per wave
  constexpr int TN = BN / WN / 16;    // o-tiles per wave
  __shared__ __align__(16) ushort_t As[BM][40];   // +8 pad: 2-way max (free)
  __shared__ __align__(16) ushort_t Bs[BN][40];
  const int t    = threadIdx.x;
  const int lane = t & 63;
  const int wave = t >> 6;
  const int quad = lane >> 4;
  const int l15  = lane & 15;
  const int wm   = wave / WN, wn = wave % WN;
  const int m_base = wm * (BM / WM);
  const int n_base = wn * (BN / WN);
  const int n0 = blockIdx.y * BM;
  const int o0 = blockIdx.x * BN;
  f32x4 acc[TM][TN] = {};

  for (int kt = 0; kt < K; kt += 32) {
    // ---- stage A tile (BM x 32) ----
    if (AF32) {
      const float* A = (const float*)Aptr;
      for (int c = t; c < BM * 4; c += 256) {
        int row = c >> 2, col8 = (c & 3) * 8;
        const float* src = A + (size_t)(n0 + row) * K + kt + col8;
        float4 f0 = *(const float4*)src;
        float4 f1 = *(const float4*)(src + 4);
        uint4 pk;
        pk.x = (unsigned)f2bf(f0.x) | ((unsigned)f2bf(f0.y) << 16);
        pk.y = (unsigned)f2bf(f0.z) | ((unsigned)f2bf(f0.w) << 16);
        pk.z = (unsigned)f2bf(f1.x) | ((unsigned)f2bf(f1.y) << 16);
        pk.w = (unsigned)f2bf(f1.z) | ((unsigned)f2bf(f1.w) << 16);
        *(uint4*)&As[row][col8] = pk;
      }
    } else {
      const ushort_t* A = (const ushort_t*)Aptr;
      for (int c = t; c < BM * 4; c += 256) {
        int row = c >> 2, col8 = (c & 3) * 8;
        *(uint4*)&As[row][col8] = *(const uint4*)(A + (size_t)(n0 + row) * K + kt + col8);
      }
    }
    // ---- stage B tile (BN x 32), bf16 source ----
    for (int c = t; c < BN * 4; c += 256) {
      int row = c >> 2, col8 = (c & 3) * 8;
      *(uint4*)&Bs[row][col8] = *(const uint4*)(Wb + (size_t)(o0 + row) * K + kt + col8);
    }
    __syncthreads();
    // ---- fragments + MFMA ----
    bf16x8 af[TM], bfr[TN];
#pragma unroll
    for (int mi = 0; mi < TM; ++mi)
      af[mi] = *(const bf16x8*)&As[m_base + mi * 16 + l15][quad * 8];
#pragma unroll
    for (int ni = 0; ni < TN; ++ni)
      bfr[ni] = *(const bf16x8*)&Bs[n_base + ni * 16 + l15][quad * 8];
#pragma unroll
    for (int mi = 0; mi < TM; ++mi)
#pragma unroll
      for (int ni = 0; ni < TN; ++ni)
        acc[mi][ni] = __builtin_amdgcn_mfma_f32_16x16x32_bf16(af[mi], bfr[ni], acc[mi][ni], 0, 0, 0);
    __syncthreads();
  }
  // ---- epilogue: C/D layout col=lane&15, row=quad*4+reg ----
#pragma unroll
  for (int mi = 0; mi < TM; ++mi) {
#pragma unroll
    for (int ni = 0; ni < TN; ++ni) {
      int col = o0 + n_base + ni * 16 + l15;
      float bv = bias[col];
      int rbase = n0 + m_base + mi * 16 + quad * 4;
#pragma unroll
      for (int r = 0; r < 4; ++r) {
        float val = acc[mi][ni][r] + bv;
        if (OUTBF16) ((ushort_t*)Cptr)[(size_t)(rbase + r) * O + col] = f2bf(val);
        else         ((float*)Cptr)[(size_t)(rbase + r) * O + col] = val;
      }
    }
  }
}

// ---------------- RoPE + elu+1 in place on (ROWS,384) fp32 buffer ----------------
__global__ void rope_elu_k(float* __restrict__ buf, int total) {
  int idx = blockIdx.x * blockDim.x + threadIdx.x;
  if (idx >= total) return;
  int row = idx / 192;
  int p   = idx - row * 192;
  int h   = p / 24;
  int dp  = p - h * 24;              // 0..23
  int j   = dp % 12;
  int n   = row & (NN_TOK - 1);
  float fy = (float)(n >> 7);
  float fx = (float)(n & 127);
  const float c0 = 1.1073093649624542f;   // log2(10000)/12
  float freq = exp2f(-(float)j * c0);
  float f1 = fy * freq;
  float f2 = fx * freq;
  float s1, c1, s2, c2;
  sincosf(f1, &s1, &c1);
  sincosf(f2, &s2, &c2);
  float* base = buf + (size_t)row * HID + h * HD + dp;
  float in1 = base[0];
  float in2 = base[24];
  float o1 = in1 * c1 - in2 * s1;
  float o2 = in2 * c2 + in1 * s2;
  o1 = (o1 > 0.f) ? o1 + 1.f : expf(o1);
  o2 = (o2 > 0.f) ? o2 + 1.f : expf(o2);
  base[0]  = o1;
  base[24] = o2;
}

// ---------------- depthwise 3x3 lepe: vnew = v + conv(v) + lepe_b (bf16 in/out) ----------------
__global__ void lepe_k(const ushort_t* __restrict__ v, const float* __restrict__ lw,
                       const float* __restrict__ lb, ushort_t* __restrict__ vnew, int total) {
  int idx = blockIdx.x * blockDim.x + threadIdx.x;
  if (idx >= total) return;
  int pix = idx / HID;
  int ch  = idx - pix * HID;
  int n   = pix & (NN_TOK - 1);
  int boff = pix - n;
  int y = n >> 7, x = n & 127;
  float wr[9];
#pragma unroll
  for (int i = 0; i < 9; ++i) wr[i] = lw[ch * 9 + i];
  float acc = lb[ch];
#pragma unroll
  for (int dy = -1; dy <= 1; ++dy) {
    int yy = y + dy;
    if ((unsigned)yy >= 128u) continue;
#pragma unroll
    for (int dx = -1; dx <= 1; ++dx) {
      int xx = x + dx;
      if ((unsigned)xx >= 128u) continue;
      acc += bf2f(v[(size_t)(boff + (yy << 7) + xx) * HID + ch]) * wr[(dy + 1) * 3 + (dx + 1)];
    }
  }
  float center = bf2f(v[(size_t)pix * HID + ch]);
  vnew[(size_t)pix * HID + ch] = f2bf(center + acc);
}

// ---------------- kv partials: per (bh,chunk) block, 48x48 partial + ksum partial ----------------
// k fp32 (ROWS,384), v bf16 (ROWS,384). grid 1024 = bh(32)*chunk(32), 512 rows/chunk.
// Each wave owns 16 rows of each 64-row stage; each lane a 6x6 register tile.
__global__ __launch_bounds__(256) void kv_partial_k(const float* __restrict__ k,
                                                    const ushort_t* __restrict__ v,
                                                    float* __restrict__ part) {
  const int bid   = blockIdx.x;
  const int chunk = bid & 31;
  const int bh    = bid >> 5;         // 0..31
  const int b     = bh >> 3;
  const int h     = bh & 7;
  const int t     = threadIdx.x;
  const int lane  = t & 63;
  const int wave  = t >> 6;
  __shared__ __align__(16) float ks[64][48];
  __shared__ __align__(16) float vs[64][48];
  __shared__ float red[2304];
  __shared__ float ksred[4][48];
  const int d0 = (lane >> 3) * 6;     // 0,6,..,42
  const int e0 = (lane & 7) * 6;
  float acc[6][6] = {};
  float ksacc = 0.f;
  const int n0 = b * NN_TOK + chunk * 512;
  for (int st = 0; st < 512; st += 64) {
    for (int c = t; c < 3072; c += 256) {
      int rr = c / 48, d = c - rr * 48;
      int n = n0 + st + rr;
      ks[rr][d] = k[(size_t)n * HID + h * HD + d];
      vs[rr][d] = bf2f(v[(size_t)n * HID + h * HD + d]);
    }
    __syncthreads();
#pragma unroll 4
    for (int rr = 0; rr < 16; ++rr) {
      int row = (wave << 4) + rr;
      float kk[6], vv[6];
      *(float2*)&kk[0] = *(const float2*)&ks[row][d0];
      *(float2*)&kk[2] = *(const float2*)&ks[row][d0 + 2];
      *(float2*)&kk[4] = *(const float2*)&ks[row][d0 + 4];
      *(float2*)&vv[0] = *(const float2*)&vs[row][e0];
      *(float2*)&vv[2] = *(const float2*)&vs[row][e0 + 2];
      *(float2*)&vv[4] = *(const float2*)&vs[row][e0 + 4];
#pragma unroll
      for (int i = 0; i < 6; ++i)
#pragma unroll
        for (int j = 0; j < 6; ++j) acc[i][j] += kk[i] * vv[j];
      if (lane < 48) ksacc += ks[row][lane];
    }
    __syncthreads();
  }
  // cross-wave reduce in LDS (barrier-sequenced)
  if (wave == 0) {
#pragma unroll
    for (int i = 0; i < 6; ++i)
#pragma unroll
      for (int j = 0; j < 6; ++j) red[(d0 + i) * 48 + e0 + j] = acc[i][j];
  }
  if (lane < 48) ksred[wave][lane] = ksacc;
  __syncthreads();
  for (int w = 1; w < 4; ++w) {
    if (wave == w) {
#pragma unroll
      for (int i = 0; i < 6; ++i)
#pragma unroll
        for (int j = 0; j < 6; ++j) red[(d0 + i) * 48 + e0 + j] += acc[i][j];
    }
    __syncthreads();
  }
  float* p = part + (size_t)bid * 2352;
  for (int c = t; c < 2304; c += 256) p[c] = red[c];
  if (t < 48) p[2304 + t] = ksred[0][t] + ksred[1][t] + ksred[2][t] + ksred[3][t];
}

// phase 2: sum 32 chunk-partials per bh -> kv (32x2304) and ksum (32x48)
__global__ void kv_phase2(const float* __restrict__ part, float* __restrict__ kvb,
                          float* __restrict__ ksum) {
  int bh = blockIdx.x;
  int t  = threadIdx.x;
  for (int c = t; c < 2352; c += 256) {
    const float* p = part + (size_t)(bh * 32) * 2352 + c;
    float s = 0.f;
    for (int ch = 0; ch < 32; ++ch) s += p[(size_t)ch * 2352];
    if (c < 2304) kvb[bh * 2304 + c] = s;
    else          ksum[bh * 48 + (c - 2304)] = s;
  }
}

// ---------------- out = (q@kv)/max(q.ksum,1e-6), LayerNorm -> oln (bf16) ----------------
__global__ __launch_bounds__(192) void attn_ln_k(const float* __restrict__ q, const float* __restrict__ kv,
                                                 const float* __restrict__ ksum, const float* __restrict__ ln_g,
                                                 const float* __restrict__ ln_b, ushort_t* __restrict__ oln) {
  const int row = blockIdx.x;
  const int b   = row >> 14;
  const int t   = threadIdx.x;        // 0..191
  __shared__ float qrow[384];
  __shared__ float denom[8];
  __shared__ float rs[192], rq[192];
  for (int u = t; u < 384; u += 192) qrow[u] = q[(size_t)row * HID + u];
  __syncthreads();
  if (t < 8) {
    const float* kss = ksum + (b * 8 + t) * 48;
    const float* qh  = qrow + t * 48;
    float s = 0.f;
#pragma unroll
    for (int d = 0; d < 48; ++d) s += qh[d] * kss[d];
    denom[t] = fmaxf(s, 1e-6f);
  }
  __syncthreads();
  float myo[2];
  float ssum = 0.f, ssq = 0.f;
#pragma unroll
  for (int i = 0; i < 2; ++i) {
    int u = t + i * 192;
    int h = u / 48, e = u - h * 48;
    const float* kvb = kv + (size_t)(b * 8 + h) * 48 * 48 + e;
    const float* qh  = qrow + h * 48;
    float s = 0.f;
#pragma unroll
    for (int d = 0; d < 48; ++d) s += qh[d] * kvb[d * 48];
    s /= denom[h];
    myo[i] = s;
    ssum += s;
    ssq  += s * s;
  }
  rs[t] = ssum; rq[t] = ssq;
  __syncthreads();
  for (int off = 96; off >= 3; off >>= 1) {
    if (t < off) { rs[t] += rs[t + off]; rq[t] += rq[t + off]; }
    __syncthreads();
  }
  float tot  = rs[0] + rs[1] + rs[2];
  float totq = rq[0] + rq[1] + rq[2];
  float mu   = tot * (1.f / 384.f);
  float var  = totq * (1.f / 384.f) - mu * mu;
  float rstd = rsqrtf(var + 1e-5f);
#pragma unroll
  for (int i = 0; i < 2; ++i) {
    int u = t + i * 192;
    oln[(size_t)row * HID + u] = f2bf((myo[i] - mu) * rstd * ln_g[u] + ln_b[u]);
  }
}

extern "C" void kernel_launch(void* const* d_in, const int* in_sizes, int n_in,
                              void* d_out, int out_size, void* d_ws, size_t ws_size,
                              hipStream_t stream) {
  const float* x      = (const float*)d_in[0];
  const float* in_w   = (const float*)d_in[1];
  const float* in_b   = (const float*)d_in[2];
  const float* qkv_w  = (const float*)d_in[3];
  const float* qkv_b  = (const float*)d_in[4];
  const float* lepe_w = (const float*)d_in[5];
  const float* lepe_b = (const float*)d_in[6];
  const float* ln_g   = (const float*)d_in[7];
  const float* ln_b   = (const float*)d_in[8];
  const float* out_w  = (const float*)d_in[9];
  const float* out_b  = (const float*)d_in[10];
  float* out = (float*)d_out;

  // workspace (float units): bufQK 25165824 | vb 6291456 | vnew 6291456 | part 2408448
  //                          Wcb 110592 | bc 1152 | owb 36864 | kv 73728 | ksum 1536  => ~161.5 MB
  float*    ws    = (float*)d_ws;
  float*    bufQK = ws;
  float*    vbF   = bufQK + (size_t)ROWS * HID;
  float*    vnewF = vbF   + (size_t)ROWS * HID / 2;
  float*    part  = vnewF + (size_t)ROWS * HID / 2;
  float*    WcbF  = part  + (size_t)1024 * 2352;
  float*    bc    = WcbF  + (size_t)QKVO * CDIM / 2;
  float*    owbF  = bc    + QKVO;
  float*    kvb   = owbF  + (size_t)CDIM * HID / 2;
  float*    ksum  = kvb   + 32 * HD * HD;
  ushort_t* vb    = (ushort_t*)vbF;
  ushort_t* vnew  = (ushort_t*)vnewF;
  ushort_t* Wcb   = (ushort_t*)WcbF;
  ushort_t* owb   = (ushort_t*)owbF;
  ushort_t* oln   = vb;                 // alias: vb dead after lepe

  const ushort_t* Wq = Wcb;
  const ushort_t* Wk = Wcb + (size_t)384 * CDIM;
  const ushort_t* Wv = Wcb + (size_t)768 * CDIM;

  combine_w<<<QKVO, CDIM, 0, stream>>>(in_w, in_b, qkv_w, qkv_b, Wcb, bc);
  cast_ow<<<(CDIM * HID + 255) / 256, 256, 0, stream>>>(out_w, owb, CDIM * HID);

  dim3 gp(HID / 128, ROWS / 128);       // (3, 512)
  int total_v     = ROWS * HID;
  int total_pairs = ROWS * 192;

  // ---- v path: GEMM v (bf16 out) -> vb, lepe -> vnew ----
  gemm_mfma<128, 128, 2, 2, true, true><<<gp, 256, 0, stream>>>(x, Wv, bc + 768, vb, CDIM, HID);
  lepe_k<<<(total_v + 255) / 256, 256, 0, stream>>>(vb, lepe_w, lepe_b, vnew, total_v);

  // ---- k path: GEMM k (fp32 out) -> bufQK, rope+elu, kv partial + phase2 ----
  gemm_mfma<128, 128, 2, 2, true, false><<<gp, 256, 0, stream>>>(x, Wk, bc + 384, bufQK, CDIM, HID);
  rope_elu_k<<<(total_pairs + 255) / 256, 256, 0, stream>>>(bufQK, total_pairs);
  kv_partial_k<<<1024, 256, 0, stream>>>(bufQK, vnew, part);
  kv_phase2<<<32, 256, 0, stream>>>(part, kvb, ksum);

  // ---- q path: GEMM q (fp32 out) -> bufQK, rope+elu, attn+LN -> oln (bf16) ----
  gemm_mfma<128, 128, 2, 2, true, false><<<gp, 256, 0, stream>>>(x, Wq, bc, bufQK, CDIM, HID);
  rope_elu_k<<<(total_pairs + 255) / 256, 256, 0, stream>>>(bufQK, total_pairs);
  attn_ln_k<<<ROWS, 192, 0, stream>>>(bufQK, kvb, ksum, ln_g, ln_b, oln);

  // ---- final projection: oln (bf16) @ out_w^T -> out (fp32) ----
  dim3 g6(CDIM / 64, ROWS / 128);       // (3, 512)
  gemm_mfma<128, 64, 4, 1, false, false><<<g6, 256, 0, stream>>>(oln, owb, out_b, out, HID, CDIM);
}

// Round 4
// 664.073 us; speedup vs baseline: 2.2421x; 1.2131x over previous
//
#include <hip/hip_runtime.h>
#include <cstdint>
#include <cstddef>

#define NN_TOK 16384
#define ROWS   65536      // B*N
#define CDIM   192
#define HID    384
#define NHEAD  8
#define HD     48
#define QKVO   1152

typedef unsigned short ushort_t;
typedef __bf16 bf16x8 __attribute__((ext_vector_type(8)));
typedef float  f32x4  __attribute__((ext_vector_type(4)));

__device__ __forceinline__ ushort_t f2bf(float f) {
  unsigned int u = __float_as_uint(f);
  u += 0x7fffu + ((u >> 16) & 1u);          // round-to-nearest-even
  return (ushort_t)(u >> 16);
}
__device__ __forceinline__ float bf2f(ushort_t u) {
  return __uint_as_float(((unsigned int)u) << 16);
}

// ---------------- K0: combine input projections; Wc in bf16, bc fp32 ----------------
__global__ void combine_w(const float* __restrict__ in_w, const float* __restrict__ in_b,
                          const float* __restrict__ qkv_w, const float* __restrict__ qkv_b,
                          ushort_t* __restrict__ Wcb, float* __restrict__ bc) {
  int o = blockIdx.x;        // 0..1151
  int c = threadIdx.x;       // 0..191
  const float* qw = qkv_w + o * HID;
  float s = 0.f;
  for (int m = 0; m < HID; ++m) s += qw[m] * in_w[m * CDIM + c];
  Wcb[o * CDIM + c] = f2bf(s);
  if (c == 0) {
    float sb = qkv_b[o];
    for (int m = 0; m < HID; ++m) sb += qw[m] * in_b[m];
    bc[o] = sb;
  }
}

// cast out_w (192x384 fp32) -> bf16
__global__ void cast_ow(const float* __restrict__ w, ushort_t* __restrict__ wb, int n) {
  int i = blockIdx.x * blockDim.x + threadIdx.x;
  if (i < n) wb[i] = f2bf(w[i]);
}

// ---------------- sincos table: tab[n][d], n<16384, d<48 ----------------
__global__ void build_tab(float* __restrict__ tabc, float* __restrict__ tabs) {
  int i = blockIdx.x * blockDim.x + threadIdx.x;
  if (i >= NN_TOK * 48) return;
  int n = i / 48, d = i - n * 48;
  int j = d % 12;
  float pos = (d >= 24) ? (float)(n & 127) : (float)(n >> 7);
  const float c0 = 1.1073093649624542f;   // log2(10000)/12
  float a = pos * exp2f(-(float)j * c0);
  float s, c;
  sincosf(a, &s, &c);
  tabc[i] = c;
  tabs[i] = s;
}

// ---------------- MFMA bf16 GEMM: C[n,o] = sum_k A[n,k]*W[o,k] + bias[o] ----------------
template<int BM, int BN, int WM, int WN, bool AF32, bool OUTBF16>
__global__ __launch_bounds__(256) void gemm_mfma(const void* __restrict__ Aptr,
                                                 const ushort_t* __restrict__ Wb,
                                                 const float* __restrict__ bias,
                                                 void* __restrict__ Cptr,
                                                 int K, int O) {
  constexpr int TM = BM / WM / 16;
  constexpr int TN = BN / WN / 16;
  __shared__ __align__(16) ushort_t As[BM][40];
  __shared__ __align__(16) ushort_t Bs[BN][40];
  const int t    = threadIdx.x;
  const int lane = t & 63;
  const int wave = t >> 6;
  const int quad = lane >> 4;
  const int l15  = lane & 15;
  const int wm   = wave / WN, wn = wave % WN;
  const int m_base = wm * (BM / WM);
  const int n_base = wn * (BN / WN);
  const int n0 = blockIdx.y * BM;
  const int o0 = blockIdx.x * BN;
  f32x4 acc[TM][TN] = {};

  for (int kt = 0; kt < K; kt += 32) {
    if (AF32) {
      const float* A = (const float*)Aptr;
      for (int c = t; c < BM * 4; c += 256) {
        int row = c >> 2, col8 = (c & 3) * 8;
        const float* src = A + (size_t)(n0 + row) * K + kt + col8;
        float4 f0 = *(const float4*)src;
        float4 f1 = *(const float4*)(src + 4);
        uint4 pk;
        pk.x = (unsigned)f2bf(f0.x) | ((unsigned)f2bf(f0.y) << 16);
        pk.y = (unsigned)f2bf(f0.z) | ((unsigned)f2bf(f0.w) << 16);
        pk.z = (unsigned)f2bf(f1.x) | ((unsigned)f2bf(f1.y) << 16);
        pk.w = (unsigned)f2bf(f1.z) | ((unsigned)f2bf(f1.w) << 16);
        *(uint4*)&As[row][col8] = pk;
      }
    } else {
      const ushort_t* A = (const ushort_t*)Aptr;
      for (int c = t; c < BM * 4; c += 256) {
        int row = c >> 2, col8 = (c & 3) * 8;
        *(uint4*)&As[row][col8] = *(const uint4*)(A + (size_t)(n0 + row) * K + kt + col8);
      }
    }
    for (int c = t; c < BN * 4; c += 256) {
      int row = c >> 2, col8 = (c & 3) * 8;
      *(uint4*)&Bs[row][col8] = *(const uint4*)(Wb + (size_t)(o0 + row) * K + kt + col8);
    }
    __syncthreads();
    bf16x8 af[TM], bfr[TN];
#pragma unroll
    for (int mi = 0; mi < TM; ++mi)
      af[mi] = *(const bf16x8*)&As[m_base + mi * 16 + l15][quad * 8];
#pragma unroll
    for (int ni = 0; ni < TN; ++ni)
      bfr[ni] = *(const bf16x8*)&Bs[n_base + ni * 16 + l15][quad * 8];
#pragma unroll
    for (int mi = 0; mi < TM; ++mi)
#pragma unroll
      for (int ni = 0; ni < TN; ++ni)
        acc[mi][ni] = __builtin_amdgcn_mfma_f32_16x16x32_bf16(af[mi], bfr[ni], acc[mi][ni], 0, 0, 0);
    __syncthreads();
  }
#pragma unroll
  for (int mi = 0; mi < TM; ++mi) {
#pragma unroll
    for (int ni = 0; ni < TN; ++ni) {
      int col = o0 + n_base + ni * 16 + l15;
      float bv = bias[col];
      int rbase = n0 + m_base + mi * 16 + quad * 4;
#pragma unroll
      for (int r = 0; r < 4; ++r) {
        float val = acc[mi][ni][r] + bv;
        if (OUTBF16) ((ushort_t*)Cptr)[(size_t)(rbase + r) * O + col] = f2bf(val);
        else         ((float*)Cptr)[(size_t)(rbase + r) * O + col] = val;
      }
    }
  }
}

// ---------------- depthwise 3x3 lepe: vnew = v + conv(v) + lepe_b (bf16 in/out) ----------------
__global__ void lepe_k(const ushort_t* __restrict__ v, const float* __restrict__ lw,
                       const float* __restrict__ lb, ushort_t* __restrict__ vnew, int total) {
  int idx = blockIdx.x * blockDim.x + threadIdx.x;
  if (idx >= total) return;
  int pix = idx / HID;
  int ch  = idx - pix * HID;
  int n   = pix & (NN_TOK - 1);
  int boff = pix - n;
  int y = n >> 7, x = n & 127;
  float wr[9];
#pragma unroll
  for (int i = 0; i < 9; ++i) wr[i] = lw[ch * 9 + i];
  float acc = lb[ch];
#pragma unroll
  for (int dy = -1; dy <= 1; ++dy) {
    int yy = y + dy;
    if ((unsigned)yy >= 128u) continue;
#pragma unroll
    for (int dx = -1; dx <= 1; ++dx) {
      int xx = x + dx;
      if ((unsigned)xx >= 128u) continue;
      acc += bf2f(v[(size_t)(boff + (yy << 7) + xx) * HID + ch]) * wr[(dy + 1) * 3 + (dx + 1)];
    }
  }
  float center = bf2f(v[(size_t)pix * HID + ch]);
  vnew[(size_t)pix * HID + ch] = f2bf(center + acc);
}

// ---------------- kv partials with fused RoPE+elu on k ----------------
// k raw fp32 (ROWS,384), v bf16 (ROWS,384). grid 1024 = bh(32)*chunk(32), 512 rows/chunk.
__global__ __launch_bounds__(256) void kv_partial_k(const float* __restrict__ k,
                                                    const ushort_t* __restrict__ v,
                                                    const float* __restrict__ tabc,
                                                    const float* __restrict__ tabs,
                                                    float* __restrict__ part) {
  const int bid   = blockIdx.x;
  const int chunk = bid & 31;
  const int bh    = bid >> 5;         // 0..31
  const int b     = bh >> 3;
  const int h     = bh & 7;
  const int t     = threadIdx.x;
  const int lane  = t & 63;
  const int wave  = t >> 6;
  __shared__ __align__(16) float ks[64][48];
  __shared__ __align__(16) float vs[64][48];
  __shared__ float red[2304];
  __shared__ float ksred[4][48];
  const int d0 = (lane >> 3) * 6;
  const int e0 = (lane & 7) * 6;
  float acc[6][6] = {};
  float ksacc = 0.f;
  const int n0 = b * NN_TOK + chunk * 512;
  for (int st = 0; st < 512; st += 64) {
    // k staging with fused rope+elu: 64 rows x 24 pairs
    for (int c = t; c < 1536; c += 256) {
      int rr = c / 24, dp = c - rr * 24;
      int n = n0 + st + rr;
      int nn = n & (NN_TOK - 1);
      float c1 = tabc[nn * 48 + dp],      s1 = tabs[nn * 48 + dp];
      float c2 = tabc[nn * 48 + dp + 24], s2 = tabs[nn * 48 + dp + 24];
      const float* kr = k + (size_t)n * HID + h * HD;
      float in1 = kr[dp], in2 = kr[dp + 24];
      float o1 = in1 * c1 - in2 * s1;
      float o2 = in2 * c2 + in1 * s2;
      o1 = (o1 > 0.f) ? o1 + 1.f : expf(o1);
      o2 = (o2 > 0.f) ? o2 + 1.f : expf(o2);
      ks[rr][dp]      = o1;
      ks[rr][dp + 24] = o2;
    }
    for (int c = t; c < 3072; c += 256) {
      int rr = c / 48, d = c - rr * 48;
      vs[rr][d] = bf2f(v[(size_t)(n0 + st + rr) * HID + h * HD + d]);
    }
    __syncthreads();
#pragma unroll 4
    for (int rr = 0; rr < 16; ++rr) {
      int row = (wave << 4) + rr;
      float kk[6], vv[6];
      *(float2*)&kk[0] = *(const float2*)&ks[row][d0];
      *(float2*)&kk[2] = *(const float2*)&ks[row][d0 + 2];
      *(float2*)&kk[4] = *(const float2*)&ks[row][d0 + 4];
      *(float2*)&vv[0] = *(const float2*)&vs[row][e0];
      *(float2*)&vv[2] = *(const float2*)&vs[row][e0 + 2];
      *(float2*)&vv[4] = *(const float2*)&vs[row][e0 + 4];
#pragma unroll
      for (int i = 0; i < 6; ++i)
#pragma unroll
        for (int j = 0; j < 6; ++j) acc[i][j] += kk[i] * vv[j];
      if (lane < 48) ksacc += ks[row][lane];
    }
    __syncthreads();
  }
  if (wave == 0) {
#pragma unroll
    for (int i = 0; i < 6; ++i)
#pragma unroll
      for (int j = 0; j < 6; ++j) red[(d0 + i) * 48 + e0 + j] = acc[i][j];
  }
  if (lane < 48) ksred[wave][lane] = ksacc;
  __syncthreads();
  for (int w = 1; w < 4; ++w) {
    if (wave == w) {
#pragma unroll
      for (int i = 0; i < 6; ++i)
#pragma unroll
        for (int j = 0; j < 6; ++j) red[(d0 + i) * 48 + e0 + j] += acc[i][j];
    }
    __syncthreads();
  }
  float* p = part + (size_t)bid * 2352;
  for (int c = t; c < 2304; c += 256) p[c] = red[c];
  if (t < 48) p[2304 + t] = ksred[0][t] + ksred[1][t] + ksred[2][t] + ksred[3][t];
}

// phase 2: sum 32 chunk-partials per bh -> kv (32x2304) and ksum (32x48)
__global__ void kv_phase2(const float* __restrict__ part, float* __restrict__ kvb,
                          float* __restrict__ ksum) {
  int bh = blockIdx.x;
  int t  = threadIdx.x;
  for (int c = t; c < 2352; c += 256) {
    const float* p = part + (size_t)(bh * 32) * 2352 + c;
    float s = 0.f;
    for (int ch = 0; ch < 32; ++ch) s += p[(size_t)ch * 2352];
    if (c < 2304) kvb[bh * 2304 + c] = s;
    else          ksum[bh * 48 + (c - 2304)] = s;
  }
}

// ---------------- fused: rope+elu(q) -> q@kv/denom -> LayerNorm -> oln (bf16) ----------------
// 32 rows per block, 256 threads (4 waves). Each lane: 8 rows x 6 cols register tile.
__global__ __launch_bounds__(256) void attn_ln_fused(const float* __restrict__ q,
                                                     const float* __restrict__ tabc,
                                                     const float* __restrict__ tabs,
                                                     const float* __restrict__ kvg,
                                                     const float* __restrict__ ksum,
                                                     const float* __restrict__ ln_g,
                                                     const float* __restrict__ ln_b,
                                                     ushort_t* __restrict__ oln) {
  __shared__ float qs[32][8][52];     // padded: head stride 52 -> conflict-free
  __shared__ float denomS[32][8];
  const int t    = threadIdx.x;
  const int row0 = blockIdx.x * 32;
  const int b    = row0 >> 14;
  // ---- Phase A: stage raw q ----
  for (int c = t; c < 32 * 96; c += 256) {
    int r = c / 96, u4 = (c - r * 96) * 4;
    int h = u4 / 48, d = u4 - h * 48;
    float4 v = *(const float4*)(q + (size_t)(row0 + r) * HID + u4);
    *(float4*)&qs[r][h][d] = v;
  }
  __syncthreads();
  // ---- Phase B: rope+elu in LDS; thread (r=t>>3, h=t&7) owns 24 pairs; fused denom ----
  {
    int r = t >> 3, h = t & 7;
    int n = (row0 + r) & (NN_TOK - 1);
    const float* tc  = tabc + n * 48;
    const float* ts  = tabs + n * 48;
    const float* ksh = ksum + (b * 8 + h) * 48;
    float dn = 0.f;
#pragma unroll 4
    for (int dp = 0; dp < 24; ++dp) {
      float c1 = tc[dp], s1 = ts[dp], c2 = tc[dp + 24], s2 = ts[dp + 24];
      float in1 = qs[r][h][dp], in2 = qs[r][h][dp + 24];
      float o1 = in1 * c1 - in2 * s1;
      float o2 = in2 * c2 + in1 * s2;
      o1 = (o1 > 0.f) ? o1 + 1.f : expf(o1);
      o2 = (o2 > 0.f) ? o2 + 1.f : expf(o2);
      qs[r][h][dp]      = o1;
      qs[r][h][dp + 24] = o2;
      dn += o1 * ksh[dp] + o2 * ksh[dp + 24];
    }
    denomS[r][h] = fmaxf(dn, 1e-6f);
  }
  __syncthreads();
  // ---- Phase C: q@kv, 8x6 register tile per lane ----
  const int lane = t & 63, rg = t >> 6;
  const int hh = lane >> 3;
  const int e0 = (lane & 7) * 6;
  const float* kvh = kvg + (size_t)(b * 8 + hh) * 48 * 48;
  float acc[8][6] = {};
#pragma unroll 2
  for (int d = 0; d < 48; ++d) {
    float kvv[6];
    *(float2*)&kvv[0] = *(const float2*)(kvh + d * 48 + e0);
    *(float2*)&kvv[2] = *(const float2*)(kvh + d * 48 + e0 + 2);
    *(float2*)&kvv[4] = *(const float2*)(kvh + d * 48 + e0 + 4);
#pragma unroll
    for (int i = 0; i < 8; ++i) {
      float qv = qs[rg * 8 + i][hh][d];
#pragma unroll
      for (int j = 0; j < 6; ++j) acc[i][j] += qv * kvv[j];
    }
  }
  // ---- Phase D: divide, LN (wave-wide shuffle reduce), store bf16 ----
  float gg[6], bb[6];
#pragma unroll
  for (int j = 0; j < 6; ++j) {
    gg[j] = ln_g[lane * 6 + j];
    bb[j] = ln_b[lane * 6 + j];
  }
#pragma unroll
  for (int i = 0; i < 8; ++i) {
    int r = rg * 8 + i;
    float dnm = denomS[r][hh];
    float o[6];
    float s = 0.f, sq = 0.f;
#pragma unroll
    for (int j = 0; j < 6; ++j) {
      o[j] = acc[i][j] / dnm;
      s += o[j]; sq += o[j] * o[j];
    }
#pragma unroll
    for (int m = 1; m < 64; m <<= 1) {
      s  += __shfl_xor(s, m, 64);
      sq += __shfl_xor(sq, m, 64);
    }
    float mu   = s * (1.f / 384.f);
    float var  = sq * (1.f / 384.f) - mu * mu;
    float rstd = rsqrtf(var + 1e-5f);
    unsigned pk0 = (unsigned)f2bf((o[0] - mu) * rstd * gg[0] + bb[0]) |
                   ((unsigned)f2bf((o[1] - mu) * rstd * gg[1] + bb[1]) << 16);
    unsigned pk1 = (unsigned)f2bf((o[2] - mu) * rstd * gg[2] + bb[2]) |
                   ((unsigned)f2bf((o[3] - mu) * rstd * gg[3] + bb[3]) << 16);
    unsigned pk2 = (unsigned)f2bf((o[4] - mu) * rstd * gg[4] + bb[4]) |
                   ((unsigned)f2bf((o[5] - mu) * rstd * gg[5] + bb[5]) << 16);
    unsigned* dst = (unsigned*)(oln + (size_t)(row0 + r) * HID + lane * 6);
    dst[0] = pk0; dst[1] = pk1; dst[2] = pk2;
  }
}

extern "C" void kernel_launch(void* const* d_in, const int* in_sizes, int n_in,
                              void* d_out, int out_size, void* d_ws, size_t ws_size,
                              hipStream_t stream) {
  const float* x      = (const float*)d_in[0];
  const float* in_w   = (const float*)d_in[1];
  const float* in_b   = (const float*)d_in[2];
  const float* qkv_w  = (const float*)d_in[3];
  const float* qkv_b  = (const float*)d_in[4];
  const float* lepe_w = (const float*)d_in[5];
  const float* lepe_b = (const float*)d_in[6];
  const float* ln_g   = (const float*)d_in[7];
  const float* ln_b   = (const float*)d_in[8];
  const float* out_w  = (const float*)d_in[9];
  const float* out_b  = (const float*)d_in[10];
  float* out = (float*)d_out;

  // workspace (float units) ~168 MB total
  float*    ws    = (float*)d_ws;
  float*    bufQK = ws;                                    // 25165824
  float*    vbF   = bufQK + (size_t)ROWS * HID;            // 6291456
  float*    vnewF = vbF   + (size_t)ROWS * HID / 2;        // 6291456
  float*    part  = vnewF + (size_t)ROWS * HID / 2;        // 2408448
  float*    WcbF  = part  + (size_t)1024 * 2352;           // 110592
  float*    bc    = WcbF  + (size_t)QKVO * CDIM / 2;       // 1152
  float*    owbF  = bc    + QKVO;                          // 36864
  float*    kvb   = owbF  + (size_t)CDIM * HID / 2;        // 73728
  float*    ksum  = kvb   + 32 * HD * HD;                  // 1536
  float*    tabc  = ksum  + 32 * HD;                       // 786432
  float*    tabs  = tabc  + (size_t)NN_TOK * 48;           // 786432
  ushort_t* vb    = (ushort_t*)vbF;
  ushort_t* vnew  = (ushort_t*)vnewF;
  ushort_t* Wcb   = (ushort_t*)WcbF;
  ushort_t* owb   = (ushort_t*)owbF;
  ushort_t* oln   = vb;                 // alias: vb dead after lepe

  const ushort_t* Wq = Wcb;
  const ushort_t* Wk = Wcb + (size_t)384 * CDIM;
  const ushort_t* Wv = Wcb + (size_t)768 * CDIM;

  combine_w<<<QKVO, CDIM, 0, stream>>>(in_w, in_b, qkv_w, qkv_b, Wcb, bc);
  cast_ow<<<(CDIM * HID + 255) / 256, 256, 0, stream>>>(out_w, owb, CDIM * HID);
  build_tab<<<(NN_TOK * 48 + 255) / 256, 256, 0, stream>>>(tabc, tabs);

  dim3 gp(HID / 128, ROWS / 128);       // (3, 512)
  int total_v = ROWS * HID;

  // ---- v path: GEMM v (bf16 out) -> vb, lepe -> vnew ----
  gemm_mfma<128, 128, 2, 2, true, true><<<gp, 256, 0, stream>>>(x, Wv, bc + 768, vb, CDIM, HID);
  lepe_k<<<(total_v + 255) / 256, 256, 0, stream>>>(vb, lepe_w, lepe_b, vnew, total_v);

  // ---- k path: GEMM k (fp32 raw) -> bufQK, kv partial (rope fused) + phase2 ----
  gemm_mfma<128, 128, 2, 2, true, false><<<gp, 256, 0, stream>>>(x, Wk, bc + 384, bufQK, CDIM, HID);
  kv_partial_k<<<1024, 256, 0, stream>>>(bufQK, vnew, tabc, tabs, part);
  kv_phase2<<<32, 256, 0, stream>>>(part, kvb, ksum);

  // ---- q path: GEMM q (fp32 raw) -> bufQK, fused rope+attn+LN -> oln (bf16) ----
  gemm_mfma<128, 128, 2, 2, true, false><<<gp, 256, 0, stream>>>(x, Wq, bc, bufQK, CDIM, HID);
  attn_ln_fused<<<ROWS / 32, 256, 0, stream>>>(bufQK, tabc, tabs, kvb, ksum, ln_g, ln_b, oln);

  // ---- final projection: oln (bf16) @ out_w^T -> out (fp32) ----
  dim3 g6(CDIM / 64, ROWS / 128);       // (3, 512)
  gemm_mfma<128, 64, 4, 1, false, false><<<g6, 256, 0, stream>>>(oln, owb, out_b, out, HID, CDIM);
}

// Round 5
// 617.556 us; speedup vs baseline: 2.4110x; 1.0753x over previous
//
#include <hip/hip_runtime.h>
#include <cstdint>
#include <cstddef>

#define NN_TOK 16384
#define ROWS   65536      // B*N
#define CDIM   192
#define HID    384
#define NHEAD  8
#define HD     48
#define QKVO   1152

typedef unsigned short ushort_t;
typedef __bf16 bf16x8 __attribute__((ext_vector_type(8)));
typedef float  f32x4  __attribute__((ext_vector_type(4)));

__device__ __forceinline__ ushort_t f2bf(float f) {
  unsigned int u = __float_as_uint(f);
  u += 0x7fffu + ((u >> 16) & 1u);          // round-to-nearest-even
  return (ushort_t)(u >> 16);
}
__device__ __forceinline__ float bf2f(ushort_t u) {
  return __uint_as_float(((unsigned int)u) << 16);
}

// ---------------- K0: combine input projections; Wc in bf16, bc fp32 ----------------
__global__ void combine_w(const float* __restrict__ in_w, const float* __restrict__ in_b,
                          const float* __restrict__ qkv_w, const float* __restrict__ qkv_b,
                          ushort_t* __restrict__ Wcb, float* __restrict__ bc) {
  int o = blockIdx.x;        // 0..1151
  int c = threadIdx.x;       // 0..191
  const float* qw = qkv_w + o * HID;
  float s = 0.f;
  for (int m = 0; m < HID; ++m) s += qw[m] * in_w[m * CDIM + c];
  Wcb[o * CDIM + c] = f2bf(s);
  if (c == 0) {
    float sb = qkv_b[o];
    for (int m = 0; m < HID; ++m) sb += qw[m] * in_b[m];
    bc[o] = sb;
  }
}

// cast out_w (192x384 fp32) -> bf16
__global__ void cast_ow(const float* __restrict__ w, ushort_t* __restrict__ wb, int n) {
  int i = blockIdx.x * blockDim.x + threadIdx.x;
  if (i < n) wb[i] = f2bf(w[i]);
}

// ---------------- sincos table: tab[n][d], n<16384, d<48 ----------------
__global__ void build_tab(float* __restrict__ tabc, float* __restrict__ tabs) {
  int i = blockIdx.x * blockDim.x + threadIdx.x;
  if (i >= NN_TOK * 48) return;
  int n = i / 48, d = i - n * 48;
  int j = d % 12;
  float pos = (d >= 24) ? (float)(n & 127) : (float)(n >> 7);
  const float c0 = 1.1073093649624542f;   // log2(10000)/12
  float a = pos * exp2f(-(float)j * c0);
  float s, c;
  sincosf(a, &s, &c);
  tabc[i] = c;
  tabs[i] = s;
}

// ---------------- MFMA bf16 GEMM: C[n,o] = sum_k A[n,k]*W[o,k] + bias[o] ----------------
template<int BM, int BN, int WM, int WN, bool AF32, bool OUTBF16>
__global__ __launch_bounds__(256) void gemm_mfma(const void* __restrict__ Aptr,
                                                 const ushort_t* __restrict__ Wb,
                                                 const float* __restrict__ bias,
                                                 void* __restrict__ Cptr,
                                                 int K, int O) {
  constexpr int TM = BM / WM / 16;
  constexpr int TN = BN / WN / 16;
  __shared__ __align__(16) ushort_t As[BM][40];
  __shared__ __align__(16) ushort_t Bs[BN][40];
  const int t    = threadIdx.x;
  const int lane = t & 63;
  const int wave = t >> 6;
  const int quad = lane >> 4;
  const int l15  = lane & 15;
  const int wm   = wave / WN, wn = wave % WN;
  const int m_base = wm * (BM / WM);
  const int n_base = wn * (BN / WN);
  const int n0 = blockIdx.y * BM;
  const int o0 = blockIdx.x * BN;
  f32x4 acc[TM][TN] = {};

  for (int kt = 0; kt < K; kt += 32) {
    if (AF32) {
      const float* A = (const float*)Aptr;
      for (int c = t; c < BM * 4; c += 256) {
        int row = c >> 2, col8 = (c & 3) * 8;
        const float* src = A + (size_t)(n0 + row) * K + kt + col8;
        float4 f0 = *(const float4*)src;
        float4 f1 = *(const float4*)(src + 4);
        uint4 pk;
        pk.x = (unsigned)f2bf(f0.x) | ((unsigned)f2bf(f0.y) << 16);
        pk.y = (unsigned)f2bf(f0.z) | ((unsigned)f2bf(f0.w) << 16);
        pk.z = (unsigned)f2bf(f1.x) | ((unsigned)f2bf(f1.y) << 16);
        pk.w = (unsigned)f2bf(f1.z) | ((unsigned)f2bf(f1.w) << 16);
        *(uint4*)&As[row][col8] = pk;
      }
    } else {
      const ushort_t* A = (const ushort_t*)Aptr;
      for (int c = t; c < BM * 4; c += 256) {
        int row = c >> 2, col8 = (c & 3) * 8;
        *(uint4*)&As[row][col8] = *(const uint4*)(A + (size_t)(n0 + row) * K + kt + col8);
      }
    }
    for (int c = t; c < BN * 4; c += 256) {
      int row = c >> 2, col8 = (c & 3) * 8;
      *(uint4*)&Bs[row][col8] = *(const uint4*)(Wb + (size_t)(o0 + row) * K + kt + col8);
    }
    __syncthreads();
    bf16x8 af[TM], bfr[TN];
#pragma unroll
    for (int mi = 0; mi < TM; ++mi)
      af[mi] = *(const bf16x8*)&As[m_base + mi * 16 + l15][quad * 8];
#pragma unroll
    for (int ni = 0; ni < TN; ++ni)
      bfr[ni] = *(const bf16x8*)&Bs[n_base + ni * 16 + l15][quad * 8];
#pragma unroll
    for (int mi = 0; mi < TM; ++mi)
#pragma unroll
      for (int ni = 0; ni < TN; ++ni)
        acc[mi][ni] = __builtin_amdgcn_mfma_f32_16x16x32_bf16(af[mi], bfr[ni], acc[mi][ni], 0, 0, 0);
    __syncthreads();
  }
#pragma unroll
  for (int mi = 0; mi < TM; ++mi) {
#pragma unroll
    for (int ni = 0; ni < TN; ++ni) {
      int col = o0 + n_base + ni * 16 + l15;
      float bv = bias[col];
      int rbase = n0 + m_base + mi * 16 + quad * 4;
#pragma unroll
      for (int r = 0; r < 4; ++r) {
        float val = acc[mi][ni][r] + bv;
        if (OUTBF16) ((ushort_t*)Cptr)[(size_t)(rbase + r) * O + col] = f2bf(val);
        else         ((float*)Cptr)[(size_t)(rbase + r) * O + col] = val;
      }
    }
  }
}

// ---------------- channel-vectorized depthwise 3x3 lepe: vnew = v + conv(v) + lepe_b ----------------
// v, vnew bf16 (ROWS,384). One thread = 1 pixel x 8 channels. Block = 2 rows x 128 cols,
// one 8-channel group. grid (48 ch-groups, 4*64 row-pairs). Weights/bias staged in LDS.
__global__ __launch_bounds__(256) void lepe_vec(const ushort_t* __restrict__ v,
                                                const float* __restrict__ lw,
                                                const float* __restrict__ lb,
                                                ushort_t* __restrict__ vnew) {
  __shared__ float wlds[9][8];
  __shared__ float blds[8];
  const int g  = blockIdx.x;            // channel group 0..47
  const int by = blockIdx.y;            // 0..255
  const int b  = by >> 6, ypair = by & 63;
  const int t  = threadIdx.x;
  if (t < 72)  wlds[t / 8][t & 7] = lw[(g * 8 + (t & 7)) * 9 + t / 8];
  if (t >= 72 && t < 80) blds[t - 72] = lb[g * 8 + (t - 72)];
  __syncthreads();
  const int col = t & 127, ry = t >> 7;
  const int y   = ypair * 2 + ry;
  const size_t pix = (size_t)b * NN_TOK + y * 128 + col;
  const ushort_t* base = v + pix * HID + g * 8;
  float acc[8], center[8];
#pragma unroll
  for (int c = 0; c < 8; ++c) acc[c] = blds[c];
#pragma unroll
  for (int dy = -1; dy <= 1; ++dy) {
#pragma unroll
    for (int dx = -1; dx <= 1; ++dx) {
      const int tap = (dy + 1) * 3 + (dx + 1);
      const int yy = y + dy, xx = col + dx;
      const float m = ((unsigned)yy < 128u && (unsigned)xx < 128u) ? 1.f : 0.f;
      uint4 pk = *(const uint4*)(base + (dy * 128 + dx) * HID);  // memory-safe even when masked
      ushort_t uu[8];
      *(uint4*)uu = pk;
#pragma unroll
      for (int c = 0; c < 8; ++c) {
        float val = bf2f(uu[c]);
        if (dy == 0 && dx == 0) center[c] = val;
        acc[c] += (wlds[tap][c] * m) * val;
      }
    }
  }
  uint4 outp;
  unsigned w0 = (unsigned)f2bf(center[0] + acc[0]) | ((unsigned)f2bf(center[1] + acc[1]) << 16);
  unsigned w1 = (unsigned)f2bf(center[2] + acc[2]) | ((unsigned)f2bf(center[3] + acc[3]) << 16);
  unsigned w2 = (unsigned)f2bf(center[4] + acc[4]) | ((unsigned)f2bf(center[5] + acc[5]) << 16);
  unsigned w3 = (unsigned)f2bf(center[6] + acc[6]) | ((unsigned)f2bf(center[7] + acc[7]) << 16);
  outp.x = w0; outp.y = w1; outp.z = w2; outp.w = w3;
  *(uint4*)(vnew + pix * HID + g * 8) = outp;
}

// ---------------- kv partials with fused RoPE+elu on k ----------------
// k raw fp32 (ROWS,384), v bf16 (ROWS,384). grid 1024 = bh(32)*chunk(32), 512 rows/chunk.
__global__ __launch_bounds__(256) void kv_partial_k(const float* __restrict__ k,
                                                    const ushort_t* __restrict__ v,
                                                    const float* __restrict__ tabc,
                                                    const float* __restrict__ tabs,
                                                    float* __restrict__ part) {
  const int bid   = blockIdx.x;
  const int chunk = bid & 31;
  const int bh    = bid >> 5;         // 0..31
  const int b     = bh >> 3;
  const int h     = bh & 7;
  const int t     = threadIdx.x;
  const int lane  = t & 63;
  const int wave  = t >> 6;
  __shared__ __align__(16) float ks[64][48];
  __shared__ __align__(16) float vs[64][48];
  __shared__ float red[2304];
  __shared__ float ksred[4][48];
  const int d0 = (lane >> 3) * 6;
  const int e0 = (lane & 7) * 6;
  float acc[6][6] = {};
  float ksacc = 0.f;
  const int n0 = b * NN_TOK + chunk * 512;
  for (int st = 0; st < 512; st += 64) {
    // k staging with fused rope+elu: 64 rows x 24 pairs
    for (int c = t; c < 1536; c += 256) {
      int rr = c / 24, dp = c - rr * 24;
      int n = n0 + st + rr;
      int nn = n & (NN_TOK - 1);
      float c1 = tabc[nn * 48 + dp],      s1 = tabs[nn * 48 + dp];
      float c2 = tabc[nn * 48 + dp + 24], s2 = tabs[nn * 48 + dp + 24];
      const float* kr = k + (size_t)n * HID + h * HD;
      float in1 = kr[dp], in2 = kr[dp + 24];
      float o1 = in1 * c1 - in2 * s1;
      float o2 = in2 * c2 + in1 * s2;
      o1 = (o1 > 0.f) ? o1 + 1.f : expf(o1);
      o2 = (o2 > 0.f) ? o2 + 1.f : expf(o2);
      ks[rr][dp]      = o1;
      ks[rr][dp + 24] = o2;
    }
    for (int c = t; c < 3072; c += 256) {
      int rr = c / 48, d = c - rr * 48;
      vs[rr][d] = bf2f(v[(size_t)(n0 + st + rr) * HID + h * HD + d]);
    }
    __syncthreads();
#pragma unroll 4
    for (int rr = 0; rr < 16; ++rr) {
      int row = (wave << 4) + rr;
      float kk[6], vv[6];
      *(float2*)&kk[0] = *(const float2*)&ks[row][d0];
      *(float2*)&kk[2] = *(const float2*)&ks[row][d0 + 2];
      *(float2*)&kk[4] = *(const float2*)&ks[row][d0 + 4];
      *(float2*)&vv[0] = *(const float2*)&vs[row][e0];
      *(float2*)&vv[2] = *(const float2*)&vs[row][e0 + 2];
      *(float2*)&vv[4] = *(const float2*)&vs[row][e0 + 4];
#pragma unroll
      for (int i = 0; i < 6; ++i)
#pragma unroll
        for (int j = 0; j < 6; ++j) acc[i][j] += kk[i] * vv[j];
      if (lane < 48) ksacc += ks[row][lane];
    }
    __syncthreads();
  }
  if (wave == 0) {
#pragma unroll
    for (int i = 0; i < 6; ++i)
#pragma unroll
      for (int j = 0; j < 6; ++j) red[(d0 + i) * 48 + e0 + j] = acc[i][j];
  }
  if (lane < 48) ksred[wave][lane] = ksacc;
  __syncthreads();
  for (int w = 1; w < 4; ++w) {
    if (wave == w) {
#pragma unroll
      for (int i = 0; i < 6; ++i)
#pragma unroll
        for (int j = 0; j < 6; ++j) red[(d0 + i) * 48 + e0 + j] += acc[i][j];
    }
    __syncthreads();
  }
  float* p = part + (size_t)bid * 2352;
  for (int c = t; c < 2304; c += 256) p[c] = red[c];
  if (t < 48) p[2304 + t] = ksred[0][t] + ksred[1][t] + ksred[2][t] + ksred[3][t];
}

// phase 2: sum 32 chunk-partials per bh -> kv (32x2304) and ksum (32x48)
__global__ void kv_phase2(const float* __restrict__ part, float* __restrict__ kvb,
                          float* __restrict__ ksum) {
  int bh = blockIdx.x;
  int t  = threadIdx.x;
  for (int c = t; c < 2352; c += 256) {
    const float* p = part + (size_t)(bh * 32) * 2352 + c;
    float s = 0.f;
    for (int ch = 0; ch < 32; ++ch) s += p[(size_t)ch * 2352];
    if (c < 2304) kvb[bh * 2304 + c] = s;
    else          ksum[bh * 48 + (c - 2304)] = s;
  }
}

// ---------------- fused: rope+elu(q) -> q@kv/denom -> LayerNorm -> oln (bf16) ----------------
// 32 rows per block, 256 threads (4 waves). Each lane: 8 rows x 6 cols register tile.
__global__ __launch_bounds__(256) void attn_ln_fused(const float* __restrict__ q,
                                                     const float* __restrict__ tabc,
                                                     const float* __restrict__ tabs,
                                                     const float* __restrict__ kvg,
                                                     const float* __restrict__ ksum,
                                                     const float* __restrict__ ln_g,
                                                     const float* __restrict__ ln_b,
                                                     ushort_t* __restrict__ oln) {
  __shared__ float qs[32][8][52];     // padded: head stride 52 -> conflict-free
  __shared__ float denomS[32][8];
  const int t    = threadIdx.x;
  const int row0 = blockIdx.x * 32;
  const int b    = row0 >> 14;
  // ---- Phase A: stage raw q ----
  for (int c = t; c < 32 * 96; c += 256) {
    int r = c / 96, u4 = (c - r * 96) * 4;
    int h = u4 / 48, d = u4 - h * 48;
    float4 v = *(const float4*)(q + (size_t)(row0 + r) * HID + u4);
    *(float4*)&qs[r][h][d] = v;
  }
  __syncthreads();
  // ---- Phase B: rope+elu in LDS; thread (r=t>>3, h=t&7) owns 24 pairs; fused denom ----
  {
    int r = t >> 3, h = t & 7;
    int n = (row0 + r) & (NN_TOK - 1);
    const float* tc  = tabc + n * 48;
    const float* ts  = tabs + n * 48;
    const float* ksh = ksum + (b * 8 + h) * 48;
    float dn = 0.f;
#pragma unroll 4
    for (int dp = 0; dp < 24; ++dp) {
      float c1 = tc[dp], s1 = ts[dp], c2 = tc[dp + 24], s2 = ts[dp + 24];
      float in1 = qs[r][h][dp], in2 = qs[r][h][dp + 24];
      float o1 = in1 * c1 - in2 * s1;
      float o2 = in2 * c2 + in1 * s2;
      o1 = (o1 > 0.f) ? o1 + 1.f : expf(o1);
      o2 = (o2 > 0.f) ? o2 + 1.f : expf(o2);
      qs[r][h][dp]      = o1;
      qs[r][h][dp + 24] = o2;
      dn += o1 * ksh[dp] + o2 * ksh[dp + 24];
    }
    denomS[r][h] = fmaxf(dn, 1e-6f);
  }
  __syncthreads();
  // ---- Phase C: q@kv, 8x6 register tile per lane ----
  const int lane = t & 63, rg = t >> 6;
  const int hh = lane >> 3;
  const int e0 = (lane & 7) * 6;
  const float* kvh = kvg + (size_t)(b * 8 + hh) * 48 * 48;
  float acc[8][6] = {};
#pragma unroll 2
  for (int d = 0; d < 48; ++d) {
    float kvv[6];
    *(float2*)&kvv[0] = *(const float2*)(kvh + d * 48 + e0);
    *(float2*)&kvv[2] = *(const float2*)(kvh + d * 48 + e0 + 2);
    *(float2*)&kvv[4] = *(const float2*)(kvh + d * 48 + e0 + 4);
#pragma unroll
    for (int i = 0; i < 8; ++i) {
      float qv = qs[rg * 8 + i][hh][d];
#pragma unroll
      for (int j = 0; j < 6; ++j) acc[i][j] += qv * kvv[j];
    }
  }
  // ---- Phase D: divide, LN (wave-wide shuffle reduce), store bf16 ----
  float gg[6], bb[6];
#pragma unroll
  for (int j = 0; j < 6; ++j) {
    gg[j] = ln_g[lane * 6 + j];
    bb[j] = ln_b[lane * 6 + j];
  }
#pragma unroll
  for (int i = 0; i < 8; ++i) {
    int r = rg * 8 + i;
    float dnm = denomS[r][hh];
    float o[6];
    float s = 0.f, sq = 0.f;
#pragma unroll
    for (int j = 0; j < 6; ++j) {
      o[j] = acc[i][j] / dnm;
      s += o[j]; sq += o[j] * o[j];
    }
#pragma unroll
    for (int m = 1; m < 64; m <<= 1) {
      s  += __shfl_xor(s, m, 64);
      sq += __shfl_xor(sq, m, 64);
    }
    float mu   = s * (1.f / 384.f);
    float var  = sq * (1.f / 384.f) - mu * mu;
    float rstd = rsqrtf(var + 1e-5f);
    unsigned pk0 = (unsigned)f2bf((o[0] - mu) * rstd * gg[0] + bb[0]) |
                   ((unsigned)f2bf((o[1] - mu) * rstd * gg[1] + bb[1]) << 16);
    unsigned pk1 = (unsigned)f2bf((o[2] - mu) * rstd * gg[2] + bb[2]) |
                   ((unsigned)f2bf((o[3] - mu) * rstd * gg[3] + bb[3]) << 16);
    unsigned pk2 = (unsigned)f2bf((o[4] - mu) * rstd * gg[4] + bb[4]) |
                   ((unsigned)f2bf((o[5] - mu) * rstd * gg[5] + bb[5]) << 16);
    unsigned* dst = (unsigned*)(oln + (size_t)(row0 + r) * HID + lane * 6);
    dst[0] = pk0; dst[1] = pk1; dst[2] = pk2;
  }
}

extern "C" void kernel_launch(void* const* d_in, const int* in_sizes, int n_in,
                              void* d_out, int out_size, void* d_ws, size_t ws_size,
                              hipStream_t stream) {
  const float* x      = (const float*)d_in[0];
  const float* in_w   = (const float*)d_in[1];
  const float* in_b   = (const float*)d_in[2];
  const float* qkv_w  = (const float*)d_in[3];
  const float* qkv_b  = (const float*)d_in[4];
  const float* lepe_w = (const float*)d_in[5];
  const float* lepe_b = (const float*)d_in[6];
  const float* ln_g   = (const float*)d_in[7];
  const float* ln_b   = (const float*)d_in[8];
  const float* out_w  = (const float*)d_in[9];
  const float* out_b  = (const float*)d_in[10];
  float* out = (float*)d_out;

  // workspace (float units) ~168 MB total
  float*    ws    = (float*)d_ws;
  float*    bufQK = ws;                                    // 25165824
  float*    vbF   = bufQK + (size_t)ROWS * HID;            // 6291456
  float*    vnewF = vbF   + (size_t)ROWS * HID / 2;        // 6291456
  float*    part  = vnewF + (size_t)ROWS * HID / 2;        // 2408448
  float*    WcbF  = part  + (size_t)1024 * 2352;           // 110592
  float*    bc    = WcbF  + (size_t)QKVO * CDIM / 2;       // 1152
  float*    owbF  = bc    + QKVO;                          // 36864
  float*    kvb   = owbF  + (size_t)CDIM * HID / 2;        // 73728
  float*    ksum  = kvb   + 32 * HD * HD;                  // 1536
  float*    tabc  = ksum  + 32 * HD;                       // 786432
  float*    tabs  = tabc  + (size_t)NN_TOK * 48;           // 786432
  ushort_t* vb    = (ushort_t*)vbF;
  ushort_t* vnew  = (ushort_t*)vnewF;
  ushort_t* Wcb   = (ushort_t*)WcbF;
  ushort_t* owb   = (ushort_t*)owbF;
  ushort_t* oln   = vb;                 // alias: vb dead after lepe

  const ushort_t* Wq = Wcb;
  const ushort_t* Wk = Wcb + (size_t)384 * CDIM;
  const ushort_t* Wv = Wcb + (size_t)768 * CDIM;

  combine_w<<<QKVO, CDIM, 0, stream>>>(in_w, in_b, qkv_w, qkv_b, Wcb, bc);
  cast_ow<<<(CDIM * HID + 255) / 256, 256, 0, stream>>>(out_w, owb, CDIM * HID);
  build_tab<<<(NN_TOK * 48 + 255) / 256, 256, 0, stream>>>(tabc, tabs);

  dim3 gp(HID / 128, ROWS / 128);       // (3, 512)

  // ---- v path: GEMM v (bf16 out) -> vb, lepe (vectorized) -> vnew ----
  gemm_mfma<128, 128, 2, 2, true, true><<<gp, 256, 0, stream>>>(x, Wv, bc + 768, vb, CDIM, HID);
  lepe_vec<<<dim3(48, 256), 256, 0, stream>>>(vb, lepe_w, lepe_b, vnew);

  // ---- k path: GEMM k (fp32 raw) -> bufQK, kv partial (rope fused) + phase2 ----
  gemm_mfma<128, 128, 2, 2, true, false><<<gp, 256, 0, stream>>>(x, Wk, bc + 384, bufQK, CDIM, HID);
  kv_partial_k<<<1024, 256, 0, stream>>>(bufQK, vnew, tabc, tabs, part);
  kv_phase2<<<32, 256, 0, stream>>>(part, kvb, ksum);

  // ---- q path: GEMM q (fp32 raw) -> bufQK, fused rope+attn+LN -> oln (bf16) ----
  gemm_mfma<128, 128, 2, 2, true, false><<<gp, 256, 0, stream>>>(x, Wq, bc, bufQK, CDIM, HID);
  attn_ln_fused<<<ROWS / 32, 256, 0, stream>>>(bufQK, tabc, tabs, kvb, ksum, ln_g, ln_b, oln);

  // ---- final projection: oln (bf16) @ out_w^T -> out (fp32) ----
  dim3 g6(CDIM / 64, ROWS / 128);       // (3, 512)
  gemm_mfma<128, 64, 4, 1, false, false><<<g6, 256, 0, stream>>>(oln, owb, out_b, out, HID, CDIM);
}

// Round 6
// 538.084 us; speedup vs baseline: 2.7671x; 1.1477x over previous
//
#include <hip/hip_runtime.h>
#include <cstdint>
#include <cstddef>

#define NN_TOK 16384
#define ROWS   65536      // B*N
#define CDIM   192
#define HID    384
#define NHEAD  8
#define HD     48
#define QKVO   1152

typedef unsigned short ushort_t;
typedef __bf16 bf16x8 __attribute__((ext_vector_type(8)));
typedef float  f32x4  __attribute__((ext_vector_type(4)));

__device__ __forceinline__ ushort_t f2bf(float f) {
  unsigned int u = __float_as_uint(f);
  u += 0x7fffu + ((u >> 16) & 1u);          // round-to-nearest-even
  return (ushort_t)(u >> 16);
}
__device__ __forceinline__ float bf2f(ushort_t u) {
  return __uint_as_float(((unsigned int)u) << 16);
}

// ---------------- K0: combine input projections; Wc in bf16, bc fp32 ----------------
__global__ void combine_w(const float* __restrict__ in_w, const float* __restrict__ in_b,
                          const float* __restrict__ qkv_w, const float* __restrict__ qkv_b,
                          ushort_t* __restrict__ Wcb, float* __restrict__ bc) {
  int o = blockIdx.x;        // 0..1151
  int c = threadIdx.x;       // 0..191
  const float* qw = qkv_w + o * HID;
  float s = 0.f;
  for (int m = 0; m < HID; ++m) s += qw[m] * in_w[m * CDIM + c];
  Wcb[o * CDIM + c] = f2bf(s);
  if (c == 0) {
    float sb = qkv_b[o];
    for (int m = 0; m < HID; ++m) sb += qw[m] * in_b[m];
    bc[o] = sb;
  }
}

// cast out_w (192x384 fp32) -> bf16
__global__ void cast_ow(const float* __restrict__ w, ushort_t* __restrict__ wb, int n) {
  int i = blockIdx.x * blockDim.x + threadIdx.x;
  if (i < n) wb[i] = f2bf(w[i]);
}

// ---------------- sincos table: tab[n][d], n<16384, d<48 ----------------
__global__ void build_tab(float* __restrict__ tabc, float* __restrict__ tabs) {
  int i = blockIdx.x * blockDim.x + threadIdx.x;
  if (i >= NN_TOK * 48) return;
  int n = i / 48, d = i - n * 48;
  int j = d % 12;
  float pos = (d >= 24) ? (float)(n & 127) : (float)(n >> 7);
  const float c0 = 1.1073093649624542f;   // log2(10000)/12
  float a = pos * exp2f(-(float)j * c0);
  float s, c;
  sincosf(a, &s, &c);
  tabc[i] = c;
  tabs[i] = s;
}

// ---------------- MFMA bf16 GEMM: C[n,o] = sum_k A[n,k]*W[o,k] + bias[o] ----------------
template<int BM, int BN, int WM, int WN, bool AF32, bool OUTBF16>
__global__ __launch_bounds__(256) void gemm_mfma(const void* __restrict__ Aptr,
                                                 const ushort_t* __restrict__ Wb,
                                                 const float* __restrict__ bias,
                                                 void* __restrict__ Cptr,
                                                 int K, int O) {
  constexpr int TM = BM / WM / 16;
  constexpr int TN = BN / WN / 16;
  __shared__ __align__(16) ushort_t As[BM][40];
  __shared__ __align__(16) ushort_t Bs[BN][40];
  const int t    = threadIdx.x;
  const int lane = t & 63;
  const int wave = t >> 6;
  const int quad = lane >> 4;
  const int l15  = lane & 15;
  const int wm   = wave / WN, wn = wave % WN;
  const int m_base = wm * (BM / WM);
  const int n_base = wn * (BN / WN);
  const int n0 = blockIdx.y * BM;
  const int o0 = blockIdx.x * BN;
  f32x4 acc[TM][TN] = {};

  for (int kt = 0; kt < K; kt += 32) {
    if (AF32) {
      const float* A = (const float*)Aptr;
      for (int c = t; c < BM * 4; c += 256) {
        int row = c >> 2, col8 = (c & 3) * 8;
        const float* src = A + (size_t)(n0 + row) * K + kt + col8;
        float4 f0 = *(const float4*)src;
        float4 f1 = *(const float4*)(src + 4);
        uint4 pk;
        pk.x = (unsigned)f2bf(f0.x) | ((unsigned)f2bf(f0.y) << 16);
        pk.y = (unsigned)f2bf(f0.z) | ((unsigned)f2bf(f0.w) << 16);
        pk.z = (unsigned)f2bf(f1.x) | ((unsigned)f2bf(f1.y) << 16);
        pk.w = (unsigned)f2bf(f1.z) | ((unsigned)f2bf(f1.w) << 16);
        *(uint4*)&As[row][col8] = pk;
      }
    } else {
      const ushort_t* A = (const ushort_t*)Aptr;
      for (int c = t; c < BM * 4; c += 256) {
        int row = c >> 2, col8 = (c & 3) * 8;
        *(uint4*)&As[row][col8] = *(const uint4*)(A + (size_t)(n0 + row) * K + kt + col8);
      }
    }
    for (int c = t; c < BN * 4; c += 256) {
      int row = c >> 2, col8 = (c & 3) * 8;
      *(uint4*)&Bs[row][col8] = *(const uint4*)(Wb + (size_t)(o0 + row) * K + kt + col8);
    }
    __syncthreads();
    bf16x8 af[TM], bfr[TN];
#pragma unroll
    for (int mi = 0; mi < TM; ++mi)
      af[mi] = *(const bf16x8*)&As[m_base + mi * 16 + l15][quad * 8];
#pragma unroll
    for (int ni = 0; ni < TN; ++ni)
      bfr[ni] = *(const bf16x8*)&Bs[n_base + ni * 16 + l15][quad * 8];
#pragma unroll
    for (int mi = 0; mi < TM; ++mi)
#pragma unroll
      for (int ni = 0; ni < TN; ++ni)
        acc[mi][ni] = __builtin_amdgcn_mfma_f32_16x16x32_bf16(af[mi], bfr[ni], acc[mi][ni], 0, 0, 0);
    __syncthreads();
  }
#pragma unroll
  for (int mi = 0; mi < TM; ++mi) {
#pragma unroll
    for (int ni = 0; ni < TN; ++ni) {
      int col = o0 + n_base + ni * 16 + l15;
      float bv = bias[col];
      int rbase = n0 + m_base + mi * 16 + quad * 4;
#pragma unroll
      for (int r = 0; r < 4; ++r) {
        float val = acc[mi][ni][r] + bv;
        if (OUTBF16) ((ushort_t*)Cptr)[(size_t)(rbase + r) * O + col] = f2bf(val);
        else         ((float*)Cptr)[(size_t)(rbase + r) * O + col] = val;
      }
    }
  }
}

// ---------------- kv partials: fused RoPE+elu on k AND lepe conv on v ----------------
// k raw fp32 (ROWS,384), v raw bf16 (ROWS,384). grid 1024 = bh(32)*chunk(32), 512 rows/chunk.
// Each 64-row stage is half an image row (fixed y). vnew = v + conv3x3(v) + lepe_b computed
// during staging (clamped loads, mask-weighted taps).
__global__ __launch_bounds__(256) void kv_partial_k(const float* __restrict__ k,
                                                    const ushort_t* __restrict__ v,
                                                    const float* __restrict__ tabc,
                                                    const float* __restrict__ tabs,
                                                    const float* __restrict__ lw,
                                                    const float* __restrict__ lb,
                                                    float* __restrict__ part) {
  const int bid   = blockIdx.x;
  const int chunk = bid & 31;
  const int bh    = bid >> 5;         // 0..31
  const int b     = bh >> 3;
  const int h     = bh & 7;
  const int t     = threadIdx.x;
  const int lane  = t & 63;
  const int wave  = t >> 6;
  __shared__ __align__(16) float ks[64][48];
  __shared__ __align__(16) float vs[64][48];
  __shared__ float red[2304];
  __shared__ float ksred[4][48];
  __shared__ float wlds[9][48];
  __shared__ float blds[48];
  // stage lepe weights/bias for this head's 48 channels
  for (int c = t; c < 432; c += 256) {
    int ch = c / 9, tap = c - ch * 9;
    wlds[tap][ch] = lw[(h * HD + ch) * 9 + tap];
  }
  if (t < 48) blds[t] = lb[h * HD + t];
  const int d0 = (lane >> 3) * 6;
  const int e0 = (lane & 7) * 6;
  float acc[6][6] = {};
  float ksacc = 0.f;
  const int n0 = b * NN_TOK + chunk * 512;
  for (int st = 0; st < 512; st += 64) {
    // ---- k staging with fused rope+elu: 64 rows x 24 pairs ----
    for (int c = t; c < 1536; c += 256) {
      int rr = c / 24, dp = c - rr * 24;
      int n = n0 + st + rr;
      int nn = n & (NN_TOK - 1);
      float c1 = tabc[nn * 48 + dp],      s1 = tabs[nn * 48 + dp];
      float c2 = tabc[nn * 48 + dp + 24], s2 = tabs[nn * 48 + dp + 24];
      const float* kr = k + (size_t)n * HID + h * HD;
      float in1 = kr[dp], in2 = kr[dp + 24];
      float o1 = in1 * c1 - in2 * s1;
      float o2 = in2 * c2 + in1 * s2;
      o1 = (o1 > 0.f) ? o1 + 1.f : expf(o1);
      o2 = (o2 > 0.f) ? o2 + 1.f : expf(o2);
      ks[rr][dp]      = o1;
      ks[rr][dp + 24] = o2;
    }
    __syncthreads();   // wlds ready before first use; ks write/read ordering below
    // ---- v staging with fused lepe conv: 64 pixels x 6 groups of 8 channels ----
    {
      const int nst = chunk * 512 + st;      // 64-aligned -> fixed y
      const int y   = nst >> 7;
      const int x0  = nst & 127;             // 0 or 64
      for (int c = t; c < 384; c += 256) {
        int rr = c / 6, gg = c - rr * 6;
        int x = x0 + rr;
        float a8[8], ctr[8];
#pragma unroll
        for (int ci = 0; ci < 8; ++ci) a8[ci] = blds[gg * 8 + ci];
#pragma unroll
        for (int dy = -1; dy <= 1; ++dy) {
#pragma unroll
          for (int dx = -1; dx <= 1; ++dx) {
            int yy = y + dy, xx = x + dx;
            float m = ((unsigned)yy < 128u && (unsigned)xx < 128u) ? 1.f : 0.f;
            int yc = min(max(yy, 0), 127), xc = min(max(xx, 0), 127);
            const ushort_t* src = v + ((size_t)(b * NN_TOK + (yc << 7) + xc)) * HID + h * HD + gg * 8;
            uint4 pk = *(const uint4*)src;
            ushort_t uu[8];
            *(uint4*)uu = pk;
            const int tap = (dy + 1) * 3 + (dx + 1);
#pragma unroll
            for (int ci = 0; ci < 8; ++ci) {
              float val = bf2f(uu[ci]);
              if (dy == 0 && dx == 0) ctr[ci] = val;
              a8[ci] += (wlds[tap][gg * 8 + ci] * m) * val;
            }
          }
        }
#pragma unroll
        for (int ci = 0; ci < 8; ++ci) vs[rr][gg * 8 + ci] = ctr[ci] + a8[ci];
      }
    }
    __syncthreads();
#pragma unroll 4
    for (int rr = 0; rr < 16; ++rr) {
      int row = (wave << 4) + rr;
      float kk[6], vv[6];
      *(float2*)&kk[0] = *(const float2*)&ks[row][d0];
      *(float2*)&kk[2] = *(const float2*)&ks[row][d0 + 2];
      *(float2*)&kk[4] = *(const float2*)&ks[row][d0 + 4];
      *(float2*)&vv[0] = *(const float2*)&vs[row][e0];
      *(float2*)&vv[2] = *(const float2*)&vs[row][e0 + 2];
      *(float2*)&vv[4] = *(const float2*)&vs[row][e0 + 4];
#pragma unroll
      for (int i = 0; i < 6; ++i)
#pragma unroll
        for (int j = 0; j < 6; ++j) acc[i][j] += kk[i] * vv[j];
      if (lane < 48) ksacc += ks[row][lane];
    }
    __syncthreads();
  }
  if (wave == 0) {
#pragma unroll
    for (int i = 0; i < 6; ++i)
#pragma unroll
      for (int j = 0; j < 6; ++j) red[(d0 + i) * 48 + e0 + j] = acc[i][j];
  }
  if (lane < 48) ksred[wave][lane] = ksacc;
  __syncthreads();
  for (int w = 1; w < 4; ++w) {
    if (wave == w) {
#pragma unroll
      for (int i = 0; i < 6; ++i)
#pragma unroll
        for (int j = 0; j < 6; ++j) red[(d0 + i) * 48 + e0 + j] += acc[i][j];
    }
    __syncthreads();
  }
  float* p = part + (size_t)bid * 2352;
  for (int c = t; c < 2304; c += 256) p[c] = red[c];
  if (t < 48) p[2304 + t] = ksred[0][t] + ksred[1][t] + ksred[2][t] + ksred[3][t];
}

// phase 2: sum 32 chunk-partials per bh -> kv (32x2304) and ksum (32x48)
__global__ void kv_phase2(const float* __restrict__ part, float* __restrict__ kvb,
                          float* __restrict__ ksum) {
  int bh = blockIdx.x;
  int t  = threadIdx.x;
  for (int c = t; c < 2352; c += 256) {
    const float* p = part + (size_t)(bh * 32) * 2352 + c;
    float s = 0.f;
    for (int ch = 0; ch < 32; ++ch) s += p[(size_t)ch * 2352];
    if (c < 2304) kvb[bh * 2304 + c] = s;
    else          ksum[bh * 48 + (c - 2304)] = s;
  }
}

// ---------------- fused: rope+elu(q) -> q@kv/denom -> LayerNorm -> oln (bf16) ----------------
// 32 rows per block, 256 threads (4 waves). Each lane: 8 rows x 6 cols register tile.
__global__ __launch_bounds__(256) void attn_ln_fused(const float* __restrict__ q,
                                                     const float* __restrict__ tabc,
                                                     const float* __restrict__ tabs,
                                                     const float* __restrict__ kvg,
                                                     const float* __restrict__ ksum,
                                                     const float* __restrict__ ln_g,
                                                     const float* __restrict__ ln_b,
                                                     ushort_t* __restrict__ oln) {
  __shared__ float qs[32][8][52];     // padded: head stride 52 -> conflict-free
  __shared__ float denomS[32][8];
  const int t    = threadIdx.x;
  const int row0 = blockIdx.x * 32;
  const int b    = row0 >> 14;
  for (int c = t; c < 32 * 96; c += 256) {
    int r = c / 96, u4 = (c - r * 96) * 4;
    int h = u4 / 48, d = u4 - h * 48;
    float4 v = *(const float4*)(q + (size_t)(row0 + r) * HID + u4);
    *(float4*)&qs[r][h][d] = v;
  }
  __syncthreads();
  {
    int r = t >> 3, h = t & 7;
    int n = (row0 + r) & (NN_TOK - 1);
    const float* tc  = tabc + n * 48;
    const float* ts  = tabs + n * 48;
    const float* ksh = ksum + (b * 8 + h) * 48;
    float dn = 0.f;
#pragma unroll 4
    for (int dp = 0; dp < 24; ++dp) {
      float c1 = tc[dp], s1 = ts[dp], c2 = tc[dp + 24], s2 = ts[dp + 24];
      float in1 = qs[r][h][dp], in2 = qs[r][h][dp + 24];
      float o1 = in1 * c1 - in2 * s1;
      float o2 = in2 * c2 + in1 * s2;
      o1 = (o1 > 0.f) ? o1 + 1.f : expf(o1);
      o2 = (o2 > 0.f) ? o2 + 1.f : expf(o2);
      qs[r][h][dp]      = o1;
      qs[r][h][dp + 24] = o2;
      dn += o1 * ksh[dp] + o2 * ksh[dp + 24];
    }
    denomS[r][h] = fmaxf(dn, 1e-6f);
  }
  __syncthreads();
  const int lane = t & 63, rg = t >> 6;
  const int hh = lane >> 3;
  const int e0 = (lane & 7) * 6;
  const float* kvh = kvg + (size_t)(b * 8 + hh) * 48 * 48;
  float acc[8][6] = {};
#pragma unroll 2
  for (int d = 0; d < 48; ++d) {
    float kvv[6];
    *(float2*)&kvv[0] = *(const float2*)(kvh + d * 48 + e0);
    *(float2*)&kvv[2] = *(const float2*)(kvh + d * 48 + e0 + 2);
    *(float2*)&kvv[4] = *(const float2*)(kvh + d * 48 + e0 + 4);
#pragma unroll
    for (int i = 0; i < 8; ++i) {
      float qv = qs[rg * 8 + i][hh][d];
#pragma unroll
      for (int j = 0; j < 6; ++j) acc[i][j] += qv * kvv[j];
    }
  }
  float gg[6], bb[6];
#pragma unroll
  for (int j = 0; j < 6; ++j) {
    gg[j] = ln_g[lane * 6 + j];
    bb[j] = ln_b[lane * 6 + j];
  }
#pragma unroll
  for (int i = 0; i < 8; ++i) {
    int r = rg * 8 + i;
    float dnm = denomS[r][hh];
    float o[6];
    float s = 0.f, sq = 0.f;
#pragma unroll
    for (int j = 0; j < 6; ++j) {
      o[j] = acc[i][j] / dnm;
      s += o[j]; sq += o[j] * o[j];
    }
#pragma unroll
    for (int m = 1; m < 64; m <<= 1) {
      s  += __shfl_xor(s, m, 64);
      sq += __shfl_xor(sq, m, 64);
    }
    float mu   = s * (1.f / 384.f);
    float var  = sq * (1.f / 384.f) - mu * mu;
    float rstd = rsqrtf(var + 1e-5f);
    unsigned pk0 = (unsigned)f2bf((o[0] - mu) * rstd * gg[0] + bb[0]) |
                   ((unsigned)f2bf((o[1] - mu) * rstd * gg[1] + bb[1]) << 16);
    unsigned pk1 = (unsigned)f2bf((o[2] - mu) * rstd * gg[2] + bb[2]) |
                   ((unsigned)f2bf((o[3] - mu) * rstd * gg[3] + bb[3]) << 16);
    unsigned pk2 = (unsigned)f2bf((o[4] - mu) * rstd * gg[4] + bb[4]) |
                   ((unsigned)f2bf((o[5] - mu) * rstd * gg[5] + bb[5]) << 16);
    unsigned* dst = (unsigned*)(oln + (size_t)(row0 + r) * HID + lane * 6);
    dst[0] = pk0; dst[1] = pk1; dst[2] = pk2;
  }
}

extern "C" void kernel_launch(void* const* d_in, const int* in_sizes, int n_in,
                              void* d_out, int out_size, void* d_ws, size_t ws_size,
                              hipStream_t stream) {
  const float* x      = (const float*)d_in[0];
  const float* in_w   = (const float*)d_in[1];
  const float* in_b   = (const float*)d_in[2];
  const float* qkv_w  = (const float*)d_in[3];
  const float* qkv_b  = (const float*)d_in[4];
  const float* lepe_w = (const float*)d_in[5];
  const float* lepe_b = (const float*)d_in[6];
  const float* ln_g   = (const float*)d_in[7];
  const float* ln_b   = (const float*)d_in[8];
  const float* out_w  = (const float*)d_in[9];
  const float* out_b  = (const float*)d_in[10];
  float* out = (float*)d_out;

  // workspace (float units) ~143 MB total
  float*    ws    = (float*)d_ws;
  float*    bufQK = ws;                                    // 25165824
  float*    vbF   = bufQK + (size_t)ROWS * HID;            // 6291456
  float*    part  = vbF   + (size_t)ROWS * HID / 2;        // 2408448
  float*    WcbF  = part  + (size_t)1024 * 2352;           // 110592
  float*    bc    = WcbF  + (size_t)QKVO * CDIM / 2;       // 1152
  float*    owbF  = bc    + QKVO;                          // 36864
  float*    kvb   = owbF  + (size_t)CDIM * HID / 2;        // 73728
  float*    ksum  = kvb   + 32 * HD * HD;                  // 1536
  float*    tabc  = ksum  + 32 * HD;                       // 786432
  float*    tabs  = tabc  + (size_t)NN_TOK * 48;           // 786432
  ushort_t* vb    = (ushort_t*)vbF;
  ushort_t* Wcb   = (ushort_t*)WcbF;
  ushort_t* owb   = (ushort_t*)owbF;
  ushort_t* oln   = vb;                 // alias: vb dead after kv_partial

  const ushort_t* Wq = Wcb;
  const ushort_t* Wk = Wcb + (size_t)384 * CDIM;
  const ushort_t* Wv = Wcb + (size_t)768 * CDIM;

  combine_w<<<QKVO, CDIM, 0, stream>>>(in_w, in_b, qkv_w, qkv_b, Wcb, bc);
  cast_ow<<<(CDIM * HID + 255) / 256, 256, 0, stream>>>(out_w, owb, CDIM * HID);
  build_tab<<<(NN_TOK * 48 + 255) / 256, 256, 0, stream>>>(tabc, tabs);

  dim3 gp(HID / 128, ROWS / 128);       // (3, 512)

  // ---- v path: GEMM v (bf16 out) -> vb (conv fused into kv_partial) ----
  gemm_mfma<128, 128, 2, 2, true, true><<<gp, 256, 0, stream>>>(x, Wv, bc + 768, vb, CDIM, HID);

  // ---- k path: GEMM k (fp32 raw) -> bufQK, kv partial (rope+lepe fused) + phase2 ----
  gemm_mfma<128, 128, 2, 2, true, false><<<gp, 256, 0, stream>>>(x, Wk, bc + 384, bufQK, CDIM, HID);
  kv_partial_k<<<1024, 256, 0, stream>>>(bufQK, vb, tabc, tabs, lepe_w, lepe_b, part);
  kv_phase2<<<32, 256, 0, stream>>>(part, kvb, ksum);

  // ---- q path: GEMM q (fp32 raw) -> bufQK, fused rope+attn+LN -> oln (bf16) ----
  gemm_mfma<128, 128, 2, 2, true, false><<<gp, 256, 0, stream>>>(x, Wq, bc, bufQK, CDIM, HID);
  attn_ln_fused<<<ROWS / 32, 256, 0, stream>>>(bufQK, tabc, tabs, kvb, ksum, ln_g, ln_b, oln);

  // ---- final projection: oln (bf16) @ out_w^T -> out (fp32) ----
  dim3 g6(CDIM / 64, ROWS / 128);       // (3, 512)
  gemm_mfma<128, 64, 4, 1, false, false><<<g6, 256, 0, stream>>>(oln, owb, out_b, out, HID, CDIM);
}

// Round 7
// 468.286 us; speedup vs baseline: 3.1796x; 1.1491x over previous
//
#include <hip/hip_runtime.h>
#include <cstdint>
#include <cstddef>

#define NN_TOK 16384
#define ROWS   65536      // B*N
#define CDIM   192
#define HID    384
#define NHEAD  8
#define HD     48
#define QKVO   1152

typedef unsigned short ushort_t;
typedef __bf16 bf16x8 __attribute__((ext_vector_type(8)));
typedef float  f32x4  __attribute__((ext_vector_type(4)));

__device__ __forceinline__ ushort_t f2bf(float f) {
  unsigned int u = __float_as_uint(f);
  u += 0x7fffu + ((u >> 16) & 1u);          // round-to-nearest-even
  return (ushort_t)(u >> 16);
}
__device__ __forceinline__ float bf2f(ushort_t u) {
  return __uint_as_float(((unsigned int)u) << 16);
}

// ---------------- cast x (fp32) -> bf16, vectorized ----------------
__global__ void cast_x(const float* __restrict__ x, ushort_t* __restrict__ xb, int n8) {
  int i = blockIdx.x * blockDim.x + threadIdx.x;
  if (i >= n8) return;
  const float4* src = (const float4*)(x + (size_t)i * 8);
  float4 f0 = src[0], f1 = src[1];
  uint4 pk;
  pk.x = (unsigned)f2bf(f0.x) | ((unsigned)f2bf(f0.y) << 16);
  pk.y = (unsigned)f2bf(f0.z) | ((unsigned)f2bf(f0.w) << 16);
  pk.z = (unsigned)f2bf(f1.x) | ((unsigned)f2bf(f1.y) << 16);
  pk.w = (unsigned)f2bf(f1.z) | ((unsigned)f2bf(f1.w) << 16);
  *(uint4*)(xb + (size_t)i * 8) = pk;
}

// ---------------- K0: combine input projections; Wc in bf16, bc fp32 ----------------
__global__ void combine_w(const float* __restrict__ in_w, const float* __restrict__ in_b,
                          const float* __restrict__ qkv_w, const float* __restrict__ qkv_b,
                          ushort_t* __restrict__ Wcb, float* __restrict__ bc) {
  int o = blockIdx.x;        // 0..1151
  int c = threadIdx.x;       // 0..191
  const float* qw = qkv_w + o * HID;
  float s = 0.f;
  for (int m = 0; m < HID; ++m) s += qw[m] * in_w[m * CDIM + c];
  Wcb[o * CDIM + c] = f2bf(s);
  if (c == 0) {
    float sb = qkv_b[o];
    for (int m = 0; m < HID; ++m) sb += qw[m] * in_b[m];
    bc[o] = sb;
  }
}

// cast out_w (192x384 fp32) -> bf16
__global__ void cast_ow(const float* __restrict__ w, ushort_t* __restrict__ wb, int n) {
  int i = blockIdx.x * blockDim.x + threadIdx.x;
  if (i < n) wb[i] = f2bf(w[i]);
}

// ---------------- packed rope table: tab4[n][dp] = (cos1,sin1,cos2,sin2), dp<24 ----------------
__global__ void build_tab(float4* __restrict__ tab4) {
  int i = blockIdx.x * blockDim.x + threadIdx.x;
  if (i >= NN_TOK * 24) return;
  int n = i / 24, dp = i - n * 24;
  int j = dp % 12;
  const float c0 = 1.1073093649624542f;   // log2(10000)/12
  float freq = exp2f(-(float)j * c0);
  float fy = (float)(n >> 7), fx = (float)(n & 127);
  float s1, c1, s2, c2;
  sincosf(fy * freq, &s1, &c1);
  sincosf(fx * freq, &s2, &c2);
  tab4[i] = make_float4(c1, s1, c2, s2);
}

// ---------------- MFMA bf16 GEMM: C[n,o] = sum_k A[n,k]*W[o,k] + bias[o] ----------------
// A bf16 with row stride lda; W (O,K) bf16 dense; C stride O (fp32 or bf16).
template<int BM, int BN, int WM, int WN, bool OUTBF16>
__global__ __launch_bounds__(256) void gemm_mfma(const ushort_t* __restrict__ A, int lda,
                                                 const ushort_t* __restrict__ Wb,
                                                 const float* __restrict__ bias,
                                                 void* __restrict__ Cptr,
                                                 int K, int O) {
  constexpr int TM = BM / WM / 16;
  constexpr int TN = BN / WN / 16;
  __shared__ __align__(16) ushort_t As[BM][40];
  __shared__ __align__(16) ushort_t Bs[BN][40];
  const int t    = threadIdx.x;
  const int lane = t & 63;
  const int wave = t >> 6;
  const int quad = lane >> 4;
  const int l15  = lane & 15;
  const int wm   = wave / WN, wn = wave % WN;
  const int m_base = wm * (BM / WM);
  const int n_base = wn * (BN / WN);
  const int n0 = blockIdx.y * BM;
  const int o0 = blockIdx.x * BN;
  f32x4 acc[TM][TN] = {};

  for (int kt = 0; kt < K; kt += 32) {
    for (int c = t; c < BM * 4; c += 256) {
      int row = c >> 2, col8 = (c & 3) * 8;
      *(uint4*)&As[row][col8] = *(const uint4*)(A + (size_t)(n0 + row) * lda + kt + col8);
    }
    for (int c = t; c < BN * 4; c += 256) {
      int row = c >> 2, col8 = (c & 3) * 8;
      *(uint4*)&Bs[row][col8] = *(const uint4*)(Wb + (size_t)(o0 + row) * K + kt + col8);
    }
    __syncthreads();
    bf16x8 af[TM], bfr[TN];
#pragma unroll
    for (int mi = 0; mi < TM; ++mi)
      af[mi] = *(const bf16x8*)&As[m_base + mi * 16 + l15][quad * 8];
#pragma unroll
    for (int ni = 0; ni < TN; ++ni)
      bfr[ni] = *(const bf16x8*)&Bs[n_base + ni * 16 + l15][quad * 8];
#pragma unroll
    for (int mi = 0; mi < TM; ++mi)
#pragma unroll
      for (int ni = 0; ni < TN; ++ni)
        acc[mi][ni] = __builtin_amdgcn_mfma_f32_16x16x32_bf16(af[mi], bfr[ni], acc[mi][ni], 0, 0, 0);
    __syncthreads();
  }
#pragma unroll
  for (int mi = 0; mi < TM; ++mi) {
#pragma unroll
    for (int ni = 0; ni < TN; ++ni) {
      int col = o0 + n_base + ni * 16 + l15;
      float bv = bias[col];
      int rbase = n0 + m_base + mi * 16 + quad * 4;
#pragma unroll
      for (int r = 0; r < 4; ++r) {
        float val = acc[mi][ni][r] + bv;
        if (OUTBF16) ((ushort_t*)Cptr)[(size_t)(rbase + r) * O + col] = f2bf(val);
        else         ((float*)Cptr)[(size_t)(rbase + r) * O + col] = val;
      }
    }
  }
}

// ---------------- kv partials: fused RoPE+elu on k AND lepe conv on v ----------------
// kq, vq: bf16 slices of qkvb (row stride 1152). grid 2048 = bh(32)*chunk(64), 256 rows/chunk.
__global__ __launch_bounds__(256) void kv_partial_k(const ushort_t* __restrict__ kq,
                                                    const ushort_t* __restrict__ vq,
                                                    const float4* __restrict__ tab4,
                                                    const float* __restrict__ lw,
                                                    const float* __restrict__ lb,
                                                    float* __restrict__ part) {
  const int bid   = blockIdx.x;
  const int chunk = bid & 63;
  const int bh    = bid >> 6;         // 0..31
  const int b     = bh >> 3;
  const int h     = bh & 7;
  const int t     = threadIdx.x;
  const int lane  = t & 63;
  const int wave  = t >> 6;
  __shared__ __align__(16) float ks[64][48];
  __shared__ __align__(16) float vs[64][48];
  __shared__ float wlds[9][48];
  __shared__ float blds[48];
  float* red   = &ks[0][0];           // 2304 floats, aliased after main loop
  float* ksred = &vs[0][0];           // 4*48 floats, aliased after main loop
  for (int c = t; c < 432; c += 256) {
    int ch = c / 9, tap = c - ch * 9;
    wlds[tap][ch] = lw[(h * HD + ch) * 9 + tap];
  }
  if (t < 48) blds[t] = lb[h * HD + t];
  __syncthreads();
  const int d0 = (lane >> 3) * 6;
  const int e0 = (lane & 7) * 6;
  float acc[6][6] = {};
  float ksacc = 0.f;
  const int n0 = b * NN_TOK + chunk * 256;
  for (int st = 0; st < 256; st += 64) {
    // ---- k staging with fused rope+elu: 64 rows x 3 segs of 8 pairs, threads 0..191 ----
    if (t < 192) {
      int rr = t / 3, s8 = (t - (t / 3) * 3) * 8;
      int n  = n0 + st + rr;
      int nn = n & (NN_TOK - 1);
      const ushort_t* kr = kq + (size_t)n * QKVO + h * HD;
      uint4 ka = *(const uint4*)(kr + s8);
      uint4 kb = *(const uint4*)(kr + s8 + 24);
      ushort_t ua[8], ub[8];
      *(uint4*)ua = ka; *(uint4*)ub = kb;
      const float4* t4 = tab4 + nn * 24 + s8;
      float oa[8], ob[8];
#pragma unroll
      for (int jj = 0; jj < 8; ++jj) {
        float4 cs = t4[jj];
        float in1 = bf2f(ua[jj]), in2 = bf2f(ub[jj]);
        float o1 = in1 * cs.x - in2 * cs.y;
        float o2 = in2 * cs.z + in1 * cs.w;
        oa[jj] = (o1 > 0.f) ? o1 + 1.f : expf(o1);
        ob[jj] = (o2 > 0.f) ? o2 + 1.f : expf(o2);
      }
      *(float4*)&ks[rr][s8]          = make_float4(oa[0], oa[1], oa[2], oa[3]);
      *(float4*)&ks[rr][s8 + 4]      = make_float4(oa[4], oa[5], oa[6], oa[7]);
      *(float4*)&ks[rr][24 + s8]     = make_float4(ob[0], ob[1], ob[2], ob[3]);
      *(float4*)&ks[rr][24 + s8 + 4] = make_float4(ob[4], ob[5], ob[6], ob[7]);
    }
    // ---- v staging with fused lepe conv: 64 pixels x 6 groups of 8 channels ----
    {
      const int nst = chunk * 256 + st;      // 64-aligned -> fixed y
      const int y   = nst >> 7;
      const int x0  = nst & 127;             // 0 or 64
      for (int c = t; c < 384; c += 256) {
        int rr = c / 6, gg = c - (c / 6) * 6;
        int x = x0 + rr;
        float a8[8], ctr[8];
#pragma unroll
        for (int ci = 0; ci < 8; ++ci) a8[ci] = blds[gg * 8 + ci];
#pragma unroll
        for (int dy = -1; dy <= 1; ++dy) {
#pragma unroll
          for (int dx = -1; dx <= 1; ++dx) {
            int yy = y + dy, xx = x + dx;
            float m = ((unsigned)yy < 128u && (unsigned)xx < 128u) ? 1.f : 0.f;
            int yc = min(max(yy, 0), 127), xc = min(max(xx, 0), 127);
            const ushort_t* src = vq + ((size_t)(b * NN_TOK + (yc << 7) + xc)) * QKVO + h * HD + gg * 8;
            uint4 pk = *(const uint4*)src;
            ushort_t uu[8];
            *(uint4*)uu = pk;
            const int tap = (dy + 1) * 3 + (dx + 1);
#pragma unroll
            for (int ci = 0; ci < 8; ++ci) {
              float val = bf2f(uu[ci]);
              if (dy == 0 && dx == 0) ctr[ci] = val;
              a8[ci] += (wlds[tap][gg * 8 + ci] * m) * val;
            }
          }
        }
#pragma unroll
        for (int ci = 0; ci < 8; ++ci) vs[rr][gg * 8 + ci] = ctr[ci] + a8[ci];
      }
    }
    __syncthreads();
#pragma unroll 4
    for (int rr = 0; rr < 16; ++rr) {
      int row = (wave << 4) + rr;
      float kk[6], vv[6];
      *(float2*)&kk[0] = *(const float2*)&ks[row][d0];
      *(float2*)&kk[2] = *(const float2*)&ks[row][d0 + 2];
      *(float2*)&kk[4] = *(const float2*)&ks[row][d0 + 4];
      *(float2*)&vv[0] = *(const float2*)&vs[row][e0];
      *(float2*)&vv[2] = *(const float2*)&vs[row][e0 + 2];
      *(float2*)&vv[4] = *(const float2*)&vs[row][e0 + 4];
#pragma unroll
      for (int i = 0; i < 6; ++i)
#pragma unroll
        for (int j = 0; j < 6; ++j) acc[i][j] += kk[i] * vv[j];
      if (lane < 48) ksacc += ks[row][lane];
    }
    __syncthreads();
  }
  // cross-wave reduce (red/ksred alias ks/vs; all FMA complete)
  if (wave == 0) {
#pragma unroll
    for (int i = 0; i < 6; ++i)
#pragma unroll
      for (int j = 0; j < 6; ++j) red[(d0 + i) * 48 + e0 + j] = acc[i][j];
  }
  if (lane < 48) ksred[wave * 48 + lane] = ksacc;
  __syncthreads();
  for (int w = 1; w < 4; ++w) {
    if (wave == w) {
#pragma unroll
      for (int i = 0; i < 6; ++i)
#pragma unroll
        for (int j = 0; j < 6; ++j) red[(d0 + i) * 48 + e0 + j] += acc[i][j];
    }
    __syncthreads();
  }
  float* p = part + (size_t)bid * 2352;
  for (int c = t; c < 2304; c += 256) p[c] = red[c];
  if (t < 48) p[2304 + t] = ksred[t] + ksred[48 + t] + ksred[96 + t] + ksred[144 + t];
}

// phase 2: sum 64 chunk-partials per bh -> kv (32x2304) and ksum (32x48)
__global__ void kv_phase2(const float* __restrict__ part, float* __restrict__ kvb,
                          float* __restrict__ ksum) {
  int bh  = blockIdx.x >> 3;
  int seg = blockIdx.x & 7;
  int t   = threadIdx.x;
  int cend = (seg + 1) * 294;
  for (int c = seg * 294 + t; c < cend; c += 256) {
    const float* p = part + (size_t)(bh * 64) * 2352 + c;
    float s = 0.f;
    for (int ch = 0; ch < 64; ++ch) s += p[(size_t)ch * 2352];
    if (c < 2304) kvb[bh * 2304 + c] = s;
    else          ksum[bh * 48 + (c - 2304)] = s;
  }
}

// ---------------- fused: rope+elu(q) -> q@kv/denom -> LayerNorm -> oln (bf16, strided) ----------------
// q bf16 slice of qkvb (stride 1152); oln written into k slice (stride 1152).
__global__ __launch_bounds__(256) void attn_ln_fused(const ushort_t* __restrict__ q,
                                                     const float4* __restrict__ tab4,
                                                     const float* __restrict__ kvg,
                                                     const float* __restrict__ ksum,
                                                     const float* __restrict__ ln_g,
                                                     const float* __restrict__ ln_b,
                                                     ushort_t* __restrict__ oln) {
  __shared__ __align__(16) float qs[32][8][52];
  __shared__ float denomS[32][8];
  const int t    = threadIdx.x;
  const int row0 = blockIdx.x * 32;
  const int b    = row0 >> 14;
  // ---- Phase A: stage q (bf16 -> fp32 LDS) ----
  for (int c = t; c < 1536; c += 256) {
    int r = c / 48, g = c - (c / 48) * 48;
    int h = g / 6, d = (g - h * 6) * 8;
    uint4 pk = *(const uint4*)(q + (size_t)(row0 + r) * QKVO + g * 8);
    ushort_t uu[8];
    *(uint4*)uu = pk;
    *(float4*)&qs[r][h][d]     = make_float4(bf2f(uu[0]), bf2f(uu[1]), bf2f(uu[2]), bf2f(uu[3]));
    *(float4*)&qs[r][h][d + 4] = make_float4(bf2f(uu[4]), bf2f(uu[5]), bf2f(uu[6]), bf2f(uu[7]));
  }
  __syncthreads();
  // ---- Phase B: rope+elu in LDS + denom ----
  {
    int r = t >> 3, h = t & 7;
    int n = (row0 + r) & (NN_TOK - 1);
    const float4* t4 = tab4 + n * 24;
    const float* ksh = ksum + (b * 8 + h) * 48;
    float dn = 0.f;
#pragma unroll 4
    for (int dp = 0; dp < 24; ++dp) {
      float4 cs = t4[dp];
      float in1 = qs[r][h][dp], in2 = qs[r][h][dp + 24];
      float o1 = in1 * cs.x - in2 * cs.y;
      float o2 = in2 * cs.z + in1 * cs.w;
      o1 = (o1 > 0.f) ? o1 + 1.f : expf(o1);
      o2 = (o2 > 0.f) ? o2 + 1.f : expf(o2);
      qs[r][h][dp]      = o1;
      qs[r][h][dp + 24] = o2;
      dn += o1 * ksh[dp] + o2 * ksh[dp + 24];
    }
    denomS[r][h] = fmaxf(dn, 1e-6f);
  }
  __syncthreads();
  // ---- Phase C: q@kv, 8x6 register tile per lane ----
  const int lane = t & 63, rg = t >> 6;
  const int hh = lane >> 3;
  const int e0 = (lane & 7) * 6;
  const float* kvh = kvg + (size_t)(b * 8 + hh) * 48 * 48;
  float acc[8][6] = {};
#pragma unroll 2
  for (int d = 0; d < 48; ++d) {
    float kvv[6];
    *(float2*)&kvv[0] = *(const float2*)(kvh + d * 48 + e0);
    *(float2*)&kvv[2] = *(const float2*)(kvh + d * 48 + e0 + 2);
    *(float2*)&kvv[4] = *(const float2*)(kvh + d * 48 + e0 + 4);
#pragma unroll
    for (int i = 0; i < 8; ++i) {
      float qv = qs[rg * 8 + i][hh][d];
#pragma unroll
      for (int j = 0; j < 6; ++j) acc[i][j] += qv * kvv[j];
    }
  }
  // ---- Phase D: divide, LN (wave shuffle), store bf16 strided ----
  float gg[6], bb[6];
#pragma unroll
  for (int j = 0; j < 6; ++j) {
    gg[j] = ln_g[lane * 6 + j];
    bb[j] = ln_b[lane * 6 + j];
  }
#pragma unroll
  for (int i = 0; i < 8; ++i) {
    int r = rg * 8 + i;
    float dnm = denomS[r][hh];
    float o[6];
    float s = 0.f, sq = 0.f;
#pragma unroll
    for (int j = 0; j < 6; ++j) {
      o[j] = acc[i][j] / dnm;
      s += o[j]; sq += o[j] * o[j];
    }
#pragma unroll
    for (int m = 1; m < 64; m <<= 1) {
      s  += __shfl_xor(s, m, 64);
      sq += __shfl_xor(sq, m, 64);
    }
    float mu   = s * (1.f / 384.f);
    float var  = sq * (1.f / 384.f) - mu * mu;
    float rstd = rsqrtf(var + 1e-5f);
    unsigned pk0 = (unsigned)f2bf((o[0] - mu) * rstd * gg[0] + bb[0]) |
                   ((unsigned)f2bf((o[1] - mu) * rstd * gg[1] + bb[1]) << 16);
    unsigned pk1 = (unsigned)f2bf((o[2] - mu) * rstd * gg[2] + bb[2]) |
                   ((unsigned)f2bf((o[3] - mu) * rstd * gg[3] + bb[3]) << 16);
    unsigned pk2 = (unsigned)f2bf((o[4] - mu) * rstd * gg[4] + bb[4]) |
                   ((unsigned)f2bf((o[5] - mu) * rstd * gg[5] + bb[5]) << 16);
    unsigned* dst = (unsigned*)(oln + (size_t)(row0 + r) * QKVO + lane * 6);
    dst[0] = pk0; dst[1] = pk1; dst[2] = pk2;
  }
}

extern "C" void kernel_launch(void* const* d_in, const int* in_sizes, int n_in,
                              void* d_out, int out_size, void* d_ws, size_t ws_size,
                              hipStream_t stream) {
  const float* x      = (const float*)d_in[0];
  const float* in_w   = (const float*)d_in[1];
  const float* in_b   = (const float*)d_in[2];
  const float* qkv_w  = (const float*)d_in[3];
  const float* qkv_b  = (const float*)d_in[4];
  const float* lepe_w = (const float*)d_in[5];
  const float* lepe_b = (const float*)d_in[6];
  const float* ln_g   = (const float*)d_in[7];
  const float* ln_b   = (const float*)d_in[8];
  const float* out_w  = (const float*)d_in[9];
  const float* out_b  = (const float*)d_in[10];
  float* out = (float*)d_out;

  // workspace (float units) ~183 MB total
  float*    ws     = (float*)d_ws;
  float*    qkvbF  = ws;                                     // ROWS*1152/2 = 37748736
  float*    xbF    = qkvbF + (size_t)ROWS * QKVO / 2;        // ROWS*192/2  = 6291456 (aliased by part)
  float*    WcbF   = xbF   + (size_t)ROWS * CDIM / 2;        // 110592
  float*    bc     = WcbF  + (size_t)QKVO * CDIM / 2;        // 1152
  float*    owbF   = bc    + QKVO;                           // 36864
  float*    kvb    = owbF  + (size_t)CDIM * HID / 2;         // 73728
  float*    ksum   = kvb   + 32 * HD * HD;                   // 1536
  float*    tab4F  = ksum  + 32 * HD;                        // 16384*24*4 = 1572864
  ushort_t* qkvb   = (ushort_t*)qkvbF;
  ushort_t* xb     = (ushort_t*)xbF;
  float*    part   = xbF;                                    // alias: xb dead after QKV GEMM (4816896 < 6291456)
  ushort_t* Wcb    = (ushort_t*)WcbF;
  ushort_t* owb    = (ushort_t*)owbF;
  float4*   tab4   = (float4*)tab4F;

  // prep
  cast_x<<<(ROWS * CDIM / 8 + 255) / 256, 256, 0, stream>>>(x, xb, ROWS * CDIM / 8);
  combine_w<<<QKVO, CDIM, 0, stream>>>(in_w, in_b, qkv_w, qkv_b, Wcb, bc);
  cast_ow<<<(CDIM * HID + 255) / 256, 256, 0, stream>>>(out_w, owb, CDIM * HID);
  build_tab<<<(NN_TOK * 24 + 255) / 256, 256, 0, stream>>>(tab4);

  // fused QKV projection: qkvb = xb @ Wcb^T + bc (bf16 out)
  dim3 gqkv(QKVO / 128, ROWS / 128);       // (9, 512)
  gemm_mfma<128, 128, 2, 2, true><<<gqkv, 256, 0, stream>>>(xb, CDIM, Wcb, bc, qkvb, CDIM, QKVO);

  // kv reduction with fused rope(k) + lepe conv(v)
  kv_partial_k<<<2048, 256, 0, stream>>>(qkvb + HID, qkvb + 2 * HID, tab4, lepe_w, lepe_b, part);
  kv_phase2<<<256, 256, 0, stream>>>(part, kvb, ksum);

  // fused rope(q) + attention + LN -> oln written into k slice of qkvb
  attn_ln_fused<<<ROWS / 32, 256, 0, stream>>>(qkvb, tab4, kvb, ksum, ln_g, ln_b, qkvb + HID);

  // final projection: oln (bf16, stride 1152) @ out_w^T -> out (fp32)
  dim3 g6(CDIM / 64, ROWS / 128);          // (3, 512)
  gemm_mfma<128, 64, 4, 1, false><<<g6, 256, 0, stream>>>(qkvb + HID, QKVO, owb, out_b, out, HID, CDIM);
}